// Round 4
// baseline (1546.056 us; speedup 1.0000x reference)
//
#include <hip/hip_runtime.h>

#define N_USERS  200000
#define N_ITEMS  100000
#define N_TOPICS 100
#define N_NODES  (N_USERS + N_ITEMS + N_TOPICS)
#define DIM      64
#define RB 256        // row-scan: chunks/blocks
#define RT 256        // row-scan: threads per block
#define BSHIFT 6      // 64 rows per bucket
#define NBUCKETS ((N_NODES + 63) >> BSHIFT)   // 4690
#define COLMASK 0x7FFFF   // 19 bits (N_NODES < 2^19)

// ---------- CSR build ----------

// One pass over rows: per-row histogram + per-bucket histogram.
__global__ void fused_hist_kernel(const int* __restrict__ rows,
                                  int* __restrict__ row_cnt,
                                  int* __restrict__ bkt_cnt, int n_edges) {
    int stride = gridDim.x * blockDim.x;
    for (int e = blockIdx.x * blockDim.x + threadIdx.x; e < n_edges; e += stride) {
        int r = rows[e];
        atomicAdd(&row_cnt[r], 1);
        atomicAdd(&bkt_cnt[r >> BSHIFT], 1);
    }
}

// Phase A: per-chunk sums of row_cnt.
__global__ void scan_reduce_kernel(const int* __restrict__ cnt,
                                   int* __restrict__ partial, int n) {
    __shared__ int s[RT];
    int tid   = threadIdx.x;
    int chunk = (n + RB - 1) / RB;
    int s0 = blockIdx.x * chunk;
    int s1 = min(n, s0 + chunk);
    int sum = 0;
    for (int i = s0 + tid; i < s1; i += RT) sum += cnt[i];
    s[tid] = sum;
    __syncthreads();
    for (int off = RT / 2; off > 0; off >>= 1) {
        if (tid < off) s[tid] += s[tid + off];
        __syncthreads();
    }
    if (tid == 0) partial[blockIdx.x] = s[0];
}

// Phase B: exclusive scan of the RB partials.
__global__ void scan_partials_kernel(int* __restrict__ partial) {
    __shared__ int s[RB];
    int tid = threadIdx.x;
    s[tid] = partial[tid];
    __syncthreads();
    for (int off = 1; off < RB; off <<= 1) {
        int v = (tid >= off) ? s[tid - off] : 0;
        __syncthreads();
        s[tid] += v;
        __syncthreads();
    }
    partial[tid] = tid ? s[tid - 1] : 0;
}

// Phase C: block-local scan + write row_ptr.
__global__ void scan_write_kernel(const int* __restrict__ cnt,
                                  const int* __restrict__ partial,
                                  int* __restrict__ row_ptr, int n) {
    __shared__ int tile[RT];
    __shared__ int carry;
    int tid   = threadIdx.x;
    int chunk = (n + RB - 1) / RB;
    int s0 = blockIdx.x * chunk;
    int s1 = min(n, s0 + chunk);
    if (tid == 0) carry = partial[blockIdx.x];
    __syncthreads();
    for (int base = s0; base < s1; base += RT) {
        int i = base + tid;
        int v = (i < s1) ? cnt[i] : 0;
        tile[tid] = v;
        __syncthreads();
        for (int off = 1; off < RT; off <<= 1) {
            int t = (tid >= off) ? tile[tid - off] : 0;
            __syncthreads();
            tile[tid] += t;
            __syncthreads();
        }
        if (i < s1) row_ptr[i] = carry + tile[tid] - v;
        __syncthreads();
        if (tid == RT - 1) carry += tile[RT - 1];
        __syncthreads();
    }
    if (blockIdx.x == RB - 1 && tid == 0) row_ptr[n] = carry;
}

// Single-block exclusive scan for the (small) bucket histogram.
__global__ void bucket_scan_kernel(const int* __restrict__ cnt,
                                   int* __restrict__ ptr, int n) {
    __shared__ int s[1024];
    int t  = threadIdx.x;
    int ch = (n + 1023) / 1024;
    int s0 = t * ch;
    int s1 = min(n, s0 + ch);
    int sum = 0;
    for (int i = s0; i < s1; ++i) sum += cnt[i];
    s[t] = sum;
    __syncthreads();
    for (int off = 1; off < 1024; off <<= 1) {
        int v = (t >= off) ? s[t - off] : 0;
        __syncthreads();
        s[t] += v;
        __syncthreads();
    }
    int run = t ? s[t - 1] : 0;
    for (int i = s0; i < s1; ++i) { ptr[i] = run; run += cnt[i]; }
    if (t == 1023) ptr[n] = s[1023];
}

// Pass 1: bin edges into 64-row buckets. Entry packs col(19b)+rowdelta(6b) and
// val bits. Active write tails = NBUCKETS*64B ~= 300 KB -> L2-resident.
__global__ void scatter1_kernel(const int* __restrict__ rows,
                                const int* __restrict__ cols,
                                const float* __restrict__ vals,
                                const int* __restrict__ bkt_ptr,
                                int* __restrict__ bkt_fil,
                                int2* __restrict__ bkt_buf, int n_edges) {
    int stride = gridDim.x * blockDim.x;
    for (int e = blockIdx.x * blockDim.x + threadIdx.x; e < n_edges; e += stride) {
        int r = rows[e];
        int b = r >> BSHIFT;
        int pos = bkt_ptr[b] + atomicAdd(&bkt_fil[b], 1);
        int2 p;
        p.x = cols[e] | ((r & 63) << 19);
        p.y = __float_as_int(vals[e]);
        bkt_buf[pos] = p;
    }
}

// Pass 2: one block per bucket; LDS fill counters (bucket is block-exclusive);
// writes land in the bucket's contiguous ~8.5 KB CSR span.
__global__ void scatter2_kernel(const int2* __restrict__ bkt_buf,
                                const int* __restrict__ bkt_ptr,
                                const int* __restrict__ row_ptr,
                                int2* __restrict__ csr_cv) {
    __shared__ int lfill[64];
    int b = blockIdx.x;
    int t = threadIdx.x;
    if (t < 64) lfill[t] = 0;
    __syncthreads();
    int e0 = bkt_ptr[b];
    int e1 = bkt_ptr[b + 1];
    int rbase = b << BSHIFT;
    for (int e = e0 + t; e < e1; e += blockDim.x) {
        int2 p = bkt_buf[e];
        int delta = ((unsigned)p.x) >> 19;
        int pos = row_ptr[rbase + delta] + atomicAdd(&lfill[delta], 1);
        int2 cv;
        cv.x = p.x & COLMASK;
        cv.y = p.y;
        csr_cv[pos] = cv;
    }
}

// ---------- SpMV: 1 wave/row, 8 edges in flight, float4 per lane ----------
__global__ void spmv_csr_kernel(const int* __restrict__ row_ptr,
                                const int2* __restrict__ csr_cv,
                                const float* __restrict__ h_src,
                                float* __restrict__ h_dst) {
    int wid  = (int)(((long)blockIdx.x * blockDim.x + threadIdx.x) >> 6);
    int lane = threadIdx.x & 63;
    if (wid >= N_NODES) return;
    int g   = lane >> 4;     // edge slot 0..3
    int l16 = lane & 15;     // float4 index within 64-dim row
    int p0 = row_ptr[wid];
    int p1 = row_ptr[wid + 1];
    float4 acc = make_float4(0.f, 0.f, 0.f, 0.f);
    for (int base = p0; base < p1; base += 8) {
        int e0 = base + g;
        int e1 = base + 4 + g;
        bool k0 = e0 < p1;
        bool k1 = e1 < p1;
        int2 cv0 = csr_cv[k0 ? e0 : p0];
        int2 cv1 = csr_cv[k1 ? e1 : p0];
        float v0 = k0 ? __int_as_float(cv0.y) : 0.f;
        float v1 = k1 ? __int_as_float(cv1.y) : 0.f;
        float4 s0 = ((const float4*)(h_src + (size_t)cv0.x * DIM))[l16];
        float4 s1 = ((const float4*)(h_src + (size_t)cv1.x * DIM))[l16];
        acc.x += v0 * s0.x + v1 * s1.x;
        acc.y += v0 * s0.y + v1 * s1.y;
        acc.z += v0 * s0.z + v1 * s1.z;
        acc.w += v0 * s0.w + v1 * s1.w;
    }
    acc.x += __shfl_xor(acc.x, 16, 64);  acc.x += __shfl_xor(acc.x, 32, 64);
    acc.y += __shfl_xor(acc.y, 16, 64);  acc.y += __shfl_xor(acc.y, 32, 64);
    acc.z += __shfl_xor(acc.z, 16, 64);  acc.z += __shfl_xor(acc.z, 32, 64);
    acc.w += __shfl_xor(acc.w, 16, 64);  acc.w += __shfl_xor(acc.w, 32, 64);
    if (lane < 16)
        ((float4*)(h_dst + (size_t)wid * DIM))[l16] = acc;
}

// ---------- batch-row accumulation + readout ----------

__global__ void gather_add_kernel(const float* __restrict__ h,
                                  const int* __restrict__ users,
                                  const int* __restrict__ items,
                                  float* __restrict__ u_acc,
                                  float* __restrict__ it_acc,
                                  int B, int first) {
    int gid  = blockIdx.x * blockDim.x + threadIdx.x;
    int b    = gid >> 4;
    int lane = gid & 15;
    if (b >= B) return;
    int u  = users[b];
    int it = N_USERS + items[b];
    float4 uv = ((const float4*)(h + (size_t)u  * DIM))[lane];
    float4 iv = ((const float4*)(h + (size_t)it * DIM))[lane];
    float4* up = (float4*)(u_acc  + (size_t)b * DIM) + lane;
    float4* ip = (float4*)(it_acc + (size_t)b * DIM) + lane;
    if (first) {
        *up = uv;
        *ip = iv;
    } else {
        float4 a = *up;
        a.x += uv.x; a.y += uv.y; a.z += uv.z; a.w += uv.w;
        *up = a;
        float4 c = *ip;
        c.x += iv.x; c.y += iv.y; c.z += iv.z; c.w += iv.w;
        *ip = c;
    }
}

__global__ void dot_kernel(const float* __restrict__ u_acc,
                           const float* __restrict__ it_acc,
                           float* __restrict__ out, int B) {
    int gid  = blockIdx.x * blockDim.x + threadIdx.x;
    int b    = gid >> 6;
    int lane = gid & 63;
    if (b >= B) return;
    float p = u_acc[(size_t)b * DIM + lane] * it_acc[(size_t)b * DIM + lane];
    #pragma unroll
    for (int off = 32; off > 0; off >>= 1)
        p += __shfl_down(p, off, 64);
    if (lane == 0) out[b] = p * (1.0f / 16.0f);
}

extern "C" void kernel_launch(void* const* d_in, const int* in_sizes, int n_in,
                              void* d_out, int out_size, void* d_ws, size_t ws_size,
                              hipStream_t stream) {
    const int*   users = (const int*)d_in[0];
    const int*   items = (const int*)d_in[1];
    const int*   erows = (const int*)d_in[2];
    const int*   ecols = (const int*)d_in[3];
    const float* evals = (const float*)d_in[4];
    const float* uemb  = (const float*)d_in[5];
    const float* iemb  = (const float*)d_in[6];
    const float* temb  = (const float*)d_in[7];
    float* out = (float*)d_out;

    const int n_edges = in_sizes[2];
    const int B       = in_sizes[0];

    const size_t hbytes  = (size_t)N_NODES * DIM * sizeof(float);        // 76.8 MB
    const size_t abytes  = (size_t)B * DIM * sizeof(float);              // 4.2 MB
    const size_t rpbytes = (((size_t)(N_NODES + 1) * 4 + 255) / 256) * 256;
    const size_t bbytes  = (((size_t)(NBUCKETS + 1) * 4 + 255) / 256) * 256;
    const size_t cvbytes = (size_t)n_edges * 8;

    char* ws = (char*)d_ws;
    size_t off = 0;
    float* hA      = (float*)(ws + off); off += hbytes;
    float* hB      = (float*)(ws + off); off += hbytes;
    float* u_acc   = (float*)(ws + off); off += abytes;
    float* it_acc  = (float*)(ws + off); off += abytes;
    int*   row_ptr = (int*)  (ws + off); off += rpbytes;
    int*   row_cnt = (int*)  (ws + off); off += rpbytes;
    int*   bkt_cnt = (int*)  (ws + off); off += bbytes;
    int*   bkt_ptr = (int*)  (ws + off); off += bbytes;
    int*   bkt_fil = (int*)  (ws + off); off += bbytes;
    int*   partial = (int*)  (ws + off); off += 4096;
    int2*  csr_cv  = (int2*) (ws + off); off += cvbytes;   // total ~207 MB
    int2*  bkt_buf = (int2*)hA;   // 40 MB alias; hA not populated until after CSR build

    dim3 blk(256);

    // ---- CSR build (once; reused for all 3 layers) ----
    hipMemsetAsync(row_cnt, 0, (size_t)N_NODES * 4, stream);
    hipMemsetAsync(bkt_cnt, 0, (size_t)NBUCKETS * 4, stream);
    hipMemsetAsync(bkt_fil, 0, (size_t)NBUCKETS * 4, stream);
    fused_hist_kernel<<<2048, blk, 0, stream>>>(erows, row_cnt, bkt_cnt, n_edges);
    scan_reduce_kernel  <<<RB, RT, 0, stream>>>(row_cnt, partial, N_NODES);
    scan_partials_kernel<<<1,  RB, 0, stream>>>(partial);
    scan_write_kernel   <<<RB, RT, 0, stream>>>(row_cnt, partial, row_ptr, N_NODES);
    bucket_scan_kernel  <<<1, 1024, 0, stream>>>(bkt_cnt, bkt_ptr, NBUCKETS);
    scatter1_kernel<<<2048, blk, 0, stream>>>(erows, ecols, evals, bkt_ptr, bkt_fil,
                                              bkt_buf, n_edges);
    scatter2_kernel<<<NBUCKETS, blk, 0, stream>>>(bkt_buf, bkt_ptr, row_ptr, csr_cv);

    // ---- h0 = concat(user, item, topic) (after bkt_buf alias is dead) ----
    hipMemcpyAsync(hA,                                     uemb, (size_t)N_USERS  * DIM * 4, hipMemcpyDeviceToDevice, stream);
    hipMemcpyAsync(hA + (size_t)N_USERS * DIM,             iemb, (size_t)N_ITEMS  * DIM * 4, hipMemcpyDeviceToDevice, stream);
    hipMemcpyAsync(hA + (size_t)(N_USERS + N_ITEMS) * DIM, temb, (size_t)N_TOPICS * DIM * 4, hipMemcpyDeviceToDevice, stream);

    const int gblocks = (B * 16 + 255) / 256;
    gather_add_kernel<<<gblocks, blk, 0, stream>>>(hA, users, items, u_acc, it_acc, B, 1);

    const int sblocks = (int)(((long)N_NODES * 64 + 255) / 256);
    float* src = hA;
    float* dst = hB;
    for (int l = 0; l < 3; ++l) {
        spmv_csr_kernel<<<sblocks, blk, 0, stream>>>(row_ptr, csr_cv, src, dst);
        gather_add_kernel<<<gblocks, blk, 0, stream>>>(dst, users, items, u_acc, it_acc, B, 0);
        float* t = src; src = dst; dst = t;
    }

    dot_kernel<<<(B * 64 + 255) / 256, blk, 0, stream>>>(u_acc, it_acc, out, B);
}

// Round 5
// 965.402 us; speedup vs baseline: 1.6015x; 1.6015x over previous
//
#include <hip/hip_runtime.h>

#define N_USERS  200000
#define N_ITEMS  100000
#define N_TOPICS 100
#define N_NODES  (N_USERS + N_ITEMS + N_TOPICS)
#define DIM      64
#define BSHIFT   6
#define NBUCKETS ((N_NODES + 63) >> BSHIFT)     // 4690
#define COLMASK  0x7FFFF                         // 19 bits (N_NODES < 2^19)
#define NB       256                             // binning blocks
#define M_TOT    (NBUCKETS * NB)                 // 1,200,640 partials
#define SB       256                             // scan blocks
#define CH       ((M_TOT + SB - 1) / SB)         // 4690 logical elems per scan block

// ---------- CSR build (zero global atomics) ----------

// Per-block LDS bucket histogram -> block-major partials (coalesced write).
__global__ void bucket_hist_kernel(const int* __restrict__ rows,
                                   int* __restrict__ partial, int n_edges) {
    __shared__ int h[NBUCKETS];
    for (int i = threadIdx.x; i < NBUCKETS; i += blockDim.x) h[i] = 0;
    __syncthreads();
    int stride = gridDim.x * blockDim.x;
    for (int e = blockIdx.x * blockDim.x + threadIdx.x; e < n_edges; e += stride)
        atomicAdd(&h[((unsigned)rows[e]) >> BSHIFT], 1);
    __syncthreads();
    for (int i = threadIdx.x; i < NBUCKETS; i += blockDim.x)
        partial[blockIdx.x * NBUCKETS + i] = h[i];
}

// Logical order L = bucket*NB + block; physical = block*NBUCKETS + bucket.
__device__ __forceinline__ int phys_idx(int L) {
    return (L & (NB - 1)) * NBUCKETS + (L >> 8);
}

// Scan phase 1: per-chunk sums of the logical sequence.
__global__ void scanB1_kernel(const int* __restrict__ partial,
                              int* __restrict__ psum) {
    __shared__ int s[256];
    int tid = threadIdx.x;
    int c0 = blockIdx.x * CH;
    int c1 = min(M_TOT, c0 + CH);
    int sum = 0;
    for (int L = c0 + tid; L < c1; L += 256) sum += partial[phys_idx(L)];
    s[tid] = sum;
    __syncthreads();
    for (int off = 128; off > 0; off >>= 1) {
        if (tid < off) s[tid] += s[tid + off];
        __syncthreads();
    }
    if (tid == 0) psum[blockIdx.x] = s[0];
}

// Scan phase 2: exclusive scan of SB partial sums.
__global__ void scanB2_kernel(int* __restrict__ psum) {
    __shared__ int s[SB];
    int tid = threadIdx.x;
    s[tid] = psum[tid];
    __syncthreads();
    for (int off = 1; off < SB; off <<= 1) {
        int v = (tid >= off) ? s[tid - off] : 0;
        __syncthreads();
        s[tid] += v;
        __syncthreads();
    }
    psum[tid] = tid ? s[tid - 1] : 0;
}

// Scan phase 3: exclusive positions, written in logical order (coalesced).
__global__ void scanB3_kernel(const int* __restrict__ partial,
                              const int* __restrict__ psum,
                              int* __restrict__ offs) {
    __shared__ int tile[256];
    __shared__ int carry;
    int tid = threadIdx.x;
    int c0 = blockIdx.x * CH;
    int c1 = min(M_TOT, c0 + CH);
    if (tid == 0) carry = psum[blockIdx.x];
    __syncthreads();
    for (int base = c0; base < c1; base += 256) {
        int L = base + tid;
        int v = (L < c1) ? partial[phys_idx(L)] : 0;
        tile[tid] = v;
        __syncthreads();
        for (int off = 1; off < 256; off <<= 1) {
            int t = (tid >= off) ? tile[tid - off] : 0;
            __syncthreads();
            tile[tid] += t;
            __syncthreads();
        }
        if (L < c1) offs[L] = carry + tile[tid] - v;
        __syncthreads();
        if (tid == 255) carry += tile[255];
        __syncthreads();
    }
}

// Bin edges into 64-row buckets at exact positions; LDS-only atomics.
// lpos[b] starts at this block's reserved offset within bucket b.
__global__ void scatter1_kernel(const int* __restrict__ rows,
                                const int* __restrict__ cols,
                                const float* __restrict__ vals,
                                const int* __restrict__ offs,
                                int2* __restrict__ bkt_buf, int n_edges) {
    __shared__ int lpos[NBUCKETS];
    for (int i = threadIdx.x; i < NBUCKETS; i += blockDim.x)
        lpos[i] = offs[i * NB + blockIdx.x];
    __syncthreads();
    int stride = gridDim.x * blockDim.x;
    for (int e = blockIdx.x * blockDim.x + threadIdx.x; e < n_edges; e += stride) {
        int r = rows[e];
        int b = ((unsigned)r) >> BSHIFT;
        int pos = atomicAdd(&lpos[b], 1);
        int2 p;
        p.x = cols[e] | ((r & 63) << 19);
        p.y = __float_as_int(vals[e]);
        bkt_buf[pos] = p;
    }
}

// One block per bucket: count 64 rows in LDS, scan, emit row_ptr directly
// (bucket_start + local prefix), then place edges into the contiguous span.
__global__ void scatter2_kernel(const int2* __restrict__ bkt_buf,
                                const int* __restrict__ offs,
                                int* __restrict__ row_ptr,
                                int2* __restrict__ csr_cv, int n_edges) {
    __shared__ int lcnt[64];
    __shared__ int lptr[64];
    __shared__ int lfill[64];
    int b = blockIdx.x;
    int t = threadIdx.x;
    int e0 = offs[b * NB];
    int e1 = (b == NBUCKETS - 1) ? n_edges : offs[(b + 1) * NB];
    if (t < 64) { lcnt[t] = 0; lfill[t] = 0; }
    __syncthreads();
    for (int e = e0 + t; e < e1; e += blockDim.x)
        atomicAdd(&lcnt[((unsigned)bkt_buf[e].x) >> 19], 1);
    __syncthreads();
    if (t < 64) lptr[t] = lcnt[t];
    __syncthreads();
    for (int off = 1; off < 64; off <<= 1) {
        int v = (t < 64 && t >= off) ? lptr[t - off] : 0;
        __syncthreads();
        if (t < 64) lptr[t] += v;        // inclusive
        __syncthreads();
    }
    int rbase = b << BSHIFT;
    if (t < 64) {
        int excl = e0 + lptr[t] - lcnt[t];
        lptr[t] = excl;
        if (rbase + t < N_NODES) row_ptr[rbase + t] = excl;
    }
    if (b == 0 && t == 64) row_ptr[N_NODES] = n_edges;
    __syncthreads();
    for (int e = e0 + t; e < e1; e += blockDim.x) {
        int2 p = bkt_buf[e];
        int delta = ((unsigned)p.x) >> 19;
        int pos = lptr[delta] + atomicAdd(&lfill[delta], 1);
        int2 cv;
        cv.x = p.x & COLMASK;
        cv.y = p.y;
        csr_cv[pos] = cv;
    }
}

// ---------- SpMV: 1 wave/row, 8 edges in flight, float4 per lane ----------
__global__ void spmv_csr_kernel(const int* __restrict__ row_ptr,
                                const int2* __restrict__ csr_cv,
                                const float* __restrict__ h_src,
                                float* __restrict__ h_dst) {
    int wid  = (int)(((long)blockIdx.x * blockDim.x + threadIdx.x) >> 6);
    int lane = threadIdx.x & 63;
    if (wid >= N_NODES) return;
    int g   = lane >> 4;
    int l16 = lane & 15;
    int p0 = row_ptr[wid];
    int p1 = row_ptr[wid + 1];
    float4 acc = make_float4(0.f, 0.f, 0.f, 0.f);
    for (int base = p0; base < p1; base += 8) {
        int e0 = base + g;
        int e1 = base + 4 + g;
        bool k0 = e0 < p1;
        bool k1 = e1 < p1;
        int2 cv0 = csr_cv[k0 ? e0 : p0];
        int2 cv1 = csr_cv[k1 ? e1 : p0];
        float v0 = k0 ? __int_as_float(cv0.y) : 0.f;
        float v1 = k1 ? __int_as_float(cv1.y) : 0.f;
        float4 s0 = ((const float4*)(h_src + (size_t)cv0.x * DIM))[l16];
        float4 s1 = ((const float4*)(h_src + (size_t)cv1.x * DIM))[l16];
        acc.x += v0 * s0.x + v1 * s1.x;
        acc.y += v0 * s0.y + v1 * s1.y;
        acc.z += v0 * s0.z + v1 * s1.z;
        acc.w += v0 * s0.w + v1 * s1.w;
    }
    acc.x += __shfl_xor(acc.x, 16, 64);  acc.x += __shfl_xor(acc.x, 32, 64);
    acc.y += __shfl_xor(acc.y, 16, 64);  acc.y += __shfl_xor(acc.y, 32, 64);
    acc.z += __shfl_xor(acc.z, 16, 64);  acc.z += __shfl_xor(acc.z, 32, 64);
    acc.w += __shfl_xor(acc.w, 16, 64);  acc.w += __shfl_xor(acc.w, 32, 64);
    if (lane < 16)
        ((float4*)(h_dst + (size_t)wid * DIM))[l16] = acc;
}

// ---------- batch-row accumulation + readout ----------

__global__ void gather_add_kernel(const float* __restrict__ h,
                                  const int* __restrict__ users,
                                  const int* __restrict__ items,
                                  float* __restrict__ u_acc,
                                  float* __restrict__ it_acc,
                                  int B, int first) {
    int gid  = blockIdx.x * blockDim.x + threadIdx.x;
    int b    = gid >> 4;
    int lane = gid & 15;
    if (b >= B) return;
    int u  = users[b];
    int it = N_USERS + items[b];
    float4 uv = ((const float4*)(h + (size_t)u  * DIM))[lane];
    float4 iv = ((const float4*)(h + (size_t)it * DIM))[lane];
    float4* up = (float4*)(u_acc  + (size_t)b * DIM) + lane;
    float4* ip = (float4*)(it_acc + (size_t)b * DIM) + lane;
    if (first) {
        *up = uv;
        *ip = iv;
    } else {
        float4 a = *up;
        a.x += uv.x; a.y += uv.y; a.z += uv.z; a.w += uv.w;
        *up = a;
        float4 c = *ip;
        c.x += iv.x; c.y += iv.y; c.z += iv.z; c.w += iv.w;
        *ip = c;
    }
}

__global__ void dot_kernel(const float* __restrict__ u_acc,
                           const float* __restrict__ it_acc,
                           float* __restrict__ out, int B) {
    int gid  = blockIdx.x * blockDim.x + threadIdx.x;
    int b    = gid >> 6;
    int lane = gid & 63;
    if (b >= B) return;
    float p = u_acc[(size_t)b * DIM + lane] * it_acc[(size_t)b * DIM + lane];
    #pragma unroll
    for (int off = 32; off > 0; off >>= 1)
        p += __shfl_down(p, off, 64);
    if (lane == 0) out[b] = p * (1.0f / 16.0f);
}

extern "C" void kernel_launch(void* const* d_in, const int* in_sizes, int n_in,
                              void* d_out, int out_size, void* d_ws, size_t ws_size,
                              hipStream_t stream) {
    const int*   users = (const int*)d_in[0];
    const int*   items = (const int*)d_in[1];
    const int*   erows = (const int*)d_in[2];
    const int*   ecols = (const int*)d_in[3];
    const float* evals = (const float*)d_in[4];
    const float* uemb  = (const float*)d_in[5];
    const float* iemb  = (const float*)d_in[6];
    const float* temb  = (const float*)d_in[7];
    float* out = (float*)d_out;

    const int n_edges = in_sizes[2];
    const int B       = in_sizes[0];

    const size_t hbytes  = (size_t)N_NODES * DIM * sizeof(float);   // 76.8 MB
    const size_t abytes  = (size_t)B * DIM * sizeof(float);         // 4.2 MB
    const size_t rpbytes = (((size_t)(N_NODES + 1) * 4 + 255) / 256) * 256;
    const size_t cvbytes = (size_t)n_edges * 8;

    char* ws = (char*)d_ws;
    size_t off = 0;
    float* hA      = (float*)(ws + off); off += hbytes;
    float* hB      = (float*)(ws + off); off += hbytes;
    float* u_acc   = (float*)(ws + off); off += abytes;
    float* it_acc  = (float*)(ws + off); off += abytes;
    int*   row_ptr = (int*)  (ws + off); off += rpbytes;
    int2*  csr_cv  = (int2*) (ws + off); off += cvbytes;   // ~203 MB total

    // CSR-build scratch aliases regions that are dead during the build:
    int2* bkt_buf = (int2*)hA;                       // 40 MB  (hA written later)
    int*  partial = (int*)hB;                        // 4.8 MB (hB written by spmv l0)
    int*  psum    = (int*)((char*)hB + (size_t)M_TOT * 4);
    int*  offs    = (int*)((char*)hB + (size_t)M_TOT * 4 + 4096);

    dim3 blk(256);

    // ---- CSR build: zero global atomics, zero global memsets ----
    bucket_hist_kernel<<<NB, blk, 0, stream>>>(erows, partial, n_edges);
    scanB1_kernel<<<SB, blk, 0, stream>>>(partial, psum);
    scanB2_kernel<<<1,  SB,  0, stream>>>(psum);
    scanB3_kernel<<<SB, blk, 0, stream>>>(partial, psum, offs);
    scatter1_kernel<<<NB, blk, 0, stream>>>(erows, ecols, evals, offs, bkt_buf, n_edges);
    scatter2_kernel<<<NBUCKETS, blk, 0, stream>>>(bkt_buf, offs, row_ptr, csr_cv, n_edges);

    // ---- h0 = concat(user, item, topic) (bkt_buf alias now dead) ----
    hipMemcpyAsync(hA,                                     uemb, (size_t)N_USERS  * DIM * 4, hipMemcpyDeviceToDevice, stream);
    hipMemcpyAsync(hA + (size_t)N_USERS * DIM,             iemb, (size_t)N_ITEMS  * DIM * 4, hipMemcpyDeviceToDevice, stream);
    hipMemcpyAsync(hA + (size_t)(N_USERS + N_ITEMS) * DIM, temb, (size_t)N_TOPICS * DIM * 4, hipMemcpyDeviceToDevice, stream);

    const int gblocks = (B * 16 + 255) / 256;
    gather_add_kernel<<<gblocks, blk, 0, stream>>>(hA, users, items, u_acc, it_acc, B, 1);

    const int sblocks = (int)(((long)N_NODES * 64 + 255) / 256);
    float* src = hA;
    float* dst = hB;
    for (int l = 0; l < 3; ++l) {
        spmv_csr_kernel<<<sblocks, blk, 0, stream>>>(row_ptr, csr_cv, src, dst);
        gather_add_kernel<<<gblocks, blk, 0, stream>>>(dst, users, items, u_acc, it_acc, B, 0);
        float* t = src; src = dst; dst = t;
    }

    dot_kernel<<<(B * 64 + 255) / 256, blk, 0, stream>>>(u_acc, it_acc, out, B);
}

// Round 6
// 756.665 us; speedup vs baseline: 2.0432x; 1.2759x over previous
//
#include <hip/hip_runtime.h>
#include <hip/hip_fp16.h>

#define N_USERS  200000
#define N_ITEMS  100000
#define N_TOPICS 100
#define N_NODES  (N_USERS + N_ITEMS + N_TOPICS)
#define DIM      64
#define BSHIFT   6
#define NBUCKETS ((N_NODES + 63) >> BSHIFT)     // 4690
#define COLMASK  0x7FFFF                         // 19 bits (N_NODES < 2^19)
#define NB       256                             // binning blocks
#define M_TOT    (NBUCKETS * NB)                 // 1,200,640 partials
#define SB       256                             // scan blocks
#define CH       ((M_TOT + SB - 1) / SB)

// ---------- CSR build (zero global atomics) ----------

__global__ void bucket_hist_kernel(const int* __restrict__ rows,
                                   int* __restrict__ partial, int n_edges) {
    __shared__ int h[NBUCKETS];
    for (int i = threadIdx.x; i < NBUCKETS; i += blockDim.x) h[i] = 0;
    __syncthreads();
    int stride = gridDim.x * blockDim.x;
    for (int e = blockIdx.x * blockDim.x + threadIdx.x; e < n_edges; e += stride)
        atomicAdd(&h[((unsigned)rows[e]) >> BSHIFT], 1);
    __syncthreads();
    for (int i = threadIdx.x; i < NBUCKETS; i += blockDim.x)
        partial[blockIdx.x * NBUCKETS + i] = h[i];
}

__device__ __forceinline__ int phys_idx(int L) {
    return (L & (NB - 1)) * NBUCKETS + (L >> 8);
}

__global__ void scanB1_kernel(const int* __restrict__ partial,
                              int* __restrict__ psum) {
    __shared__ int s[256];
    int tid = threadIdx.x;
    int c0 = blockIdx.x * CH;
    int c1 = min(M_TOT, c0 + CH);
    int sum = 0;
    for (int L = c0 + tid; L < c1; L += 256) sum += partial[phys_idx(L)];
    s[tid] = sum;
    __syncthreads();
    for (int off = 128; off > 0; off >>= 1) {
        if (tid < off) s[tid] += s[tid + off];
        __syncthreads();
    }
    if (tid == 0) psum[blockIdx.x] = s[0];
}

__global__ void scanB2_kernel(int* __restrict__ psum) {
    __shared__ int s[SB];
    int tid = threadIdx.x;
    s[tid] = psum[tid];
    __syncthreads();
    for (int off = 1; off < SB; off <<= 1) {
        int v = (tid >= off) ? s[tid - off] : 0;
        __syncthreads();
        s[tid] += v;
        __syncthreads();
    }
    psum[tid] = tid ? s[tid - 1] : 0;
}

__global__ void scanB3_kernel(const int* __restrict__ partial,
                              const int* __restrict__ psum,
                              int* __restrict__ offs) {
    __shared__ int tile[256];
    __shared__ int carry;
    int tid = threadIdx.x;
    int c0 = blockIdx.x * CH;
    int c1 = min(M_TOT, c0 + CH);
    if (tid == 0) carry = psum[blockIdx.x];
    __syncthreads();
    for (int base = c0; base < c1; base += 256) {
        int L = base + tid;
        int v = (L < c1) ? partial[phys_idx(L)] : 0;
        tile[tid] = v;
        __syncthreads();
        for (int off = 1; off < 256; off <<= 1) {
            int t = (tid >= off) ? tile[tid - off] : 0;
            __syncthreads();
            tile[tid] += t;
            __syncthreads();
        }
        if (L < c1) offs[L] = carry + tile[tid] - v;
        __syncthreads();
        if (tid == 255) carry += tile[255];
        __syncthreads();
    }
}

__global__ void scatter1_kernel(const int* __restrict__ rows,
                                const int* __restrict__ cols,
                                const float* __restrict__ vals,
                                const int* __restrict__ offs,
                                int2* __restrict__ bkt_buf, int n_edges) {
    __shared__ int lpos[NBUCKETS];
    for (int i = threadIdx.x; i < NBUCKETS; i += blockDim.x)
        lpos[i] = offs[i * NB + blockIdx.x];
    __syncthreads();
    int stride = gridDim.x * blockDim.x;
    for (int e = blockIdx.x * blockDim.x + threadIdx.x; e < n_edges; e += stride) {
        int r = rows[e];
        int b = ((unsigned)r) >> BSHIFT;
        int pos = atomicAdd(&lpos[b], 1);
        int2 p;
        p.x = cols[e] | ((r & 63) << 19);
        p.y = __float_as_int(vals[e]);
        bkt_buf[pos] = p;
    }
}

__global__ void scatter2_kernel(const int2* __restrict__ bkt_buf,
                                const int* __restrict__ offs,
                                int* __restrict__ row_ptr,
                                int2* __restrict__ csr_cv, int n_edges) {
    __shared__ int lcnt[64];
    __shared__ int lptr[64];
    __shared__ int lfill[64];
    int b = blockIdx.x;
    int t = threadIdx.x;
    int e0 = offs[b * NB];
    int e1 = (b == NBUCKETS - 1) ? n_edges : offs[(b + 1) * NB];
    if (t < 64) { lcnt[t] = 0; lfill[t] = 0; }
    __syncthreads();
    for (int e = e0 + t; e < e1; e += blockDim.x)
        atomicAdd(&lcnt[((unsigned)bkt_buf[e].x) >> 19], 1);
    __syncthreads();
    if (t < 64) lptr[t] = lcnt[t];
    __syncthreads();
    for (int off = 1; off < 64; off <<= 1) {
        int v = (t < 64 && t >= off) ? lptr[t - off] : 0;
        __syncthreads();
        if (t < 64) lptr[t] += v;        // inclusive
        __syncthreads();
    }
    int rbase = b << BSHIFT;
    if (t < 64) {
        int excl = e0 + lptr[t] - lcnt[t];
        lptr[t] = excl;
        if (rbase + t < N_NODES) row_ptr[rbase + t] = excl;
    }
    if (b == 0 && t == 64) row_ptr[N_NODES] = n_edges;
    __syncthreads();
    for (int e = e0 + t; e < e1; e += blockDim.x) {
        int2 p = bkt_buf[e];
        int delta = ((unsigned)p.x) >> 19;
        int pos = lptr[delta] + atomicAdd(&lfill[delta], 1);
        int2 cv;
        cv.x = p.x & COLMASK;
        cv.y = p.y;
        csr_cv[pos] = cv;
    }
}

// ---------- h0 = fp16(concat(user, item, topic)) ----------
// Each thread converts 4 consecutive floats (segment boundaries are %4 == 0).
__global__ void concat_f16_kernel(const float* __restrict__ uemb,
                                  const float* __restrict__ iemb,
                                  const float* __restrict__ temb,
                                  ushort* __restrict__ h0) {
    int g = blockIdx.x * blockDim.x + threadIdx.x;     // group of 4 elems
    long base = (long)g * 4;
    if (base >= (long)N_NODES * DIM) return;
    const float* src;
    long off;
    if (base < (long)N_USERS * DIM)                 { src = uemb; off = base; }
    else if (base < (long)(N_USERS + N_ITEMS) * DIM){ src = iemb; off = base - (long)N_USERS * DIM; }
    else                                            { src = temb; off = base - (long)(N_USERS + N_ITEMS) * DIM; }
    float4 v = *(const float4*)(src + off);
    __half2 a = __floats2half2_rn(v.x, v.y);
    __half2 b = __floats2half2_rn(v.z, v.w);
    uint2 o;
    o.x = *(unsigned*)&a;
    o.y = *(unsigned*)&b;
    ((uint2*)h0)[g] = o;
}

// ---------- SpMV: 1 wave/row, 16 edges in flight, fp16 rows, fp32 math ----
__device__ __forceinline__ float4 load_half4(const ushort* __restrict__ h,
                                             int row, int l16, float w,
                                             float4 acc) {
    uint2 r = ((const uint2*)(h + (size_t)row * DIM))[l16];
    float2 f01 = __half22float2(*(__half2*)&r.x);
    float2 f23 = __half22float2(*(__half2*)&r.y);
    acc.x += w * f01.x;
    acc.y += w * f01.y;
    acc.z += w * f23.x;
    acc.w += w * f23.y;
    return acc;
}

__global__ void spmv_csr_kernel(const int* __restrict__ row_ptr,
                                const int2* __restrict__ csr_cv,
                                const ushort* __restrict__ h_src,
                                ushort* __restrict__ h_dst) {
    int wid  = (int)(((long)blockIdx.x * blockDim.x + threadIdx.x) >> 6);
    int lane = threadIdx.x & 63;
    if (wid >= N_NODES) return;
    int g   = lane >> 4;
    int l16 = lane & 15;
    int p0 = row_ptr[wid];
    int p1 = row_ptr[wid + 1];
    float4 acc = make_float4(0.f, 0.f, 0.f, 0.f);
    for (int base = p0; base < p1; base += 16) {
        int e0 = base + g, e1 = base + 4 + g, e2 = base + 8 + g, e3 = base + 12 + g;
        bool k0 = e0 < p1, k1 = e1 < p1, k2 = e2 < p1, k3 = e3 < p1;
        int2 cv0 = csr_cv[k0 ? e0 : p0];
        int2 cv1 = csr_cv[k1 ? e1 : p0];
        int2 cv2 = csr_cv[k2 ? e2 : p0];
        int2 cv3 = csr_cv[k3 ? e3 : p0];
        float v0 = k0 ? __int_as_float(cv0.y) : 0.f;
        float v1 = k1 ? __int_as_float(cv1.y) : 0.f;
        float v2 = k2 ? __int_as_float(cv2.y) : 0.f;
        float v3 = k3 ? __int_as_float(cv3.y) : 0.f;
        acc = load_half4(h_src, cv0.x, l16, v0, acc);
        acc = load_half4(h_src, cv1.x, l16, v1, acc);
        acc = load_half4(h_src, cv2.x, l16, v2, acc);
        acc = load_half4(h_src, cv3.x, l16, v3, acc);
    }
    acc.x += __shfl_xor(acc.x, 16, 64);  acc.x += __shfl_xor(acc.x, 32, 64);
    acc.y += __shfl_xor(acc.y, 16, 64);  acc.y += __shfl_xor(acc.y, 32, 64);
    acc.z += __shfl_xor(acc.z, 16, 64);  acc.z += __shfl_xor(acc.z, 32, 64);
    acc.w += __shfl_xor(acc.w, 16, 64);  acc.w += __shfl_xor(acc.w, 32, 64);
    if (lane < 16) {
        __half2 a = __floats2half2_rn(acc.x, acc.y);
        __half2 b = __floats2half2_rn(acc.z, acc.w);
        uint2 o;
        o.x = *(unsigned*)&a;
        o.y = *(unsigned*)&b;
        ((uint2*)(h_dst + (size_t)wid * DIM))[l16] = o;
    }
}

// ---------- batch-row accumulation (fp32 acc) + readout ----------

__global__ void gather_add_kernel(const ushort* __restrict__ h,
                                  const int* __restrict__ users,
                                  const int* __restrict__ items,
                                  float* __restrict__ u_acc,
                                  float* __restrict__ it_acc,
                                  int B, int first) {
    int gid  = blockIdx.x * blockDim.x + threadIdx.x;
    int b    = gid >> 4;
    int lane = gid & 15;
    if (b >= B) return;
    int u  = users[b];
    int it = N_USERS + items[b];
    uint2 ur = ((const uint2*)(h + (size_t)u  * DIM))[lane];
    uint2 ir = ((const uint2*)(h + (size_t)it * DIM))[lane];
    float2 u01 = __half22float2(*(__half2*)&ur.x);
    float2 u23 = __half22float2(*(__half2*)&ur.y);
    float2 i01 = __half22float2(*(__half2*)&ir.x);
    float2 i23 = __half22float2(*(__half2*)&ir.y);
    float4* up = (float4*)(u_acc  + (size_t)b * DIM) + lane;
    float4* ip = (float4*)(it_acc + (size_t)b * DIM) + lane;
    if (first) {
        *up = make_float4(u01.x, u01.y, u23.x, u23.y);
        *ip = make_float4(i01.x, i01.y, i23.x, i23.y);
    } else {
        float4 a = *up;
        a.x += u01.x; a.y += u01.y; a.z += u23.x; a.w += u23.y;
        *up = a;
        float4 c = *ip;
        c.x += i01.x; c.y += i01.y; c.z += i23.x; c.w += i23.y;
        *ip = c;
    }
}

__global__ void dot_kernel(const float* __restrict__ u_acc,
                           const float* __restrict__ it_acc,
                           float* __restrict__ out, int B) {
    int gid  = blockIdx.x * blockDim.x + threadIdx.x;
    int b    = gid >> 6;
    int lane = gid & 63;
    if (b >= B) return;
    float p = u_acc[(size_t)b * DIM + lane] * it_acc[(size_t)b * DIM + lane];
    #pragma unroll
    for (int off = 32; off > 0; off >>= 1)
        p += __shfl_down(p, off, 64);
    if (lane == 0) out[b] = p * (1.0f / 16.0f);
}

extern "C" void kernel_launch(void* const* d_in, const int* in_sizes, int n_in,
                              void* d_out, int out_size, void* d_ws, size_t ws_size,
                              hipStream_t stream) {
    const int*   users = (const int*)d_in[0];
    const int*   items = (const int*)d_in[1];
    const int*   erows = (const int*)d_in[2];
    const int*   ecols = (const int*)d_in[3];
    const float* evals = (const float*)d_in[4];
    const float* uemb  = (const float*)d_in[5];
    const float* iemb  = (const float*)d_in[6];
    const float* temb  = (const float*)d_in[7];
    float* out = (float*)d_out;

    const int n_edges = in_sizes[2];
    const int B       = in_sizes[0];

    const size_t h2bytes = (((size_t)N_NODES * DIM * 2 + 255) / 256) * 256;  // 38.4 MB
    const size_t abytes  = (size_t)B * DIM * sizeof(float);                  // 4.2 MB
    const size_t rpbytes = (((size_t)(N_NODES + 1) * 4 + 255) / 256) * 256;
    const size_t cvbytes = (size_t)n_edges * 8;                              // 40 MB
    const size_t mbytes  = (((size_t)M_TOT * 4 + 255) / 256) * 256;          // 4.8 MB

    char* ws = (char*)d_ws;
    size_t off = 0;
    ushort* hA      = (ushort*)(ws + off); off += h2bytes;
    ushort* hB      = (ushort*)(ws + off); off += h2bytes;
    float*  u_acc   = (float*) (ws + off); off += abytes;
    float*  it_acc  = (float*) (ws + off); off += abytes;
    int*    row_ptr = (int*)   (ws + off); off += rpbytes;
    int2*   csr_cv  = (int2*)  (ws + off); off += cvbytes;
    int2*   bkt_buf = (int2*)  (ws + off); off += cvbytes;
    int*    partial = (int*)   (ws + off); off += mbytes;
    int*    offs    = (int*)   (ws + off); off += mbytes;
    int*    psum    = (int*)   (ws + off); off += 4096;   // ~172 MB total

    dim3 blk(256);

    // ---- CSR build: zero global atomics ----
    bucket_hist_kernel<<<NB, blk, 0, stream>>>(erows, partial, n_edges);
    scanB1_kernel<<<SB, blk, 0, stream>>>(partial, psum);
    scanB2_kernel<<<1,  SB,  0, stream>>>(psum);
    scanB3_kernel<<<SB, blk, 0, stream>>>(partial, psum, offs);
    scatter1_kernel<<<NB, blk, 0, stream>>>(erows, ecols, evals, offs, bkt_buf, n_edges);
    scatter2_kernel<<<NBUCKETS, blk, 0, stream>>>(bkt_buf, offs, row_ptr, csr_cv, n_edges);

    // ---- h0 ----
    const long n4 = (long)N_NODES * DIM / 4;
    concat_f16_kernel<<<(int)((n4 + 255) / 256), blk, 0, stream>>>(uemb, iemb, temb, hA);

    const int gblocks = (B * 16 + 255) / 256;
    gather_add_kernel<<<gblocks, blk, 0, stream>>>(hA, users, items, u_acc, it_acc, B, 1);

    const int sblocks = (int)(((long)N_NODES * 64 + 255) / 256);
    ushort* src = hA;
    ushort* dst = hB;
    for (int l = 0; l < 3; ++l) {
        spmv_csr_kernel<<<sblocks, blk, 0, stream>>>(row_ptr, csr_cv, src, dst);
        gather_add_kernel<<<gblocks, blk, 0, stream>>>(dst, users, items, u_acc, it_acc, B, 0);
        ushort* t = src; src = dst; dst = t;
    }

    dot_kernel<<<(B * 64 + 255) / 256, blk, 0, stream>>>(u_acc, it_acc, out, B);
}

// Round 7
// 722.487 us; speedup vs baseline: 2.1399x; 1.0473x over previous
//
#include <hip/hip_runtime.h>
#include <hip/hip_fp16.h>

#define N_USERS  200000
#define N_ITEMS  100000
#define N_TOPICS 100
#define N_NODES  (N_USERS + N_ITEMS + N_TOPICS)
#define DIM      64
#define BSHIFT   9                                // 512 rows per bucket
#define BROWS    (1 << BSHIFT)
#define NBUCKETS ((N_NODES + BROWS - 1) >> BSHIFT)   // 587
#define COLMASK  0x7FFFF                          // 19 bits (N_NODES < 2^19)
#define NB       512                              // binning blocks
#define NBSHIFT  9
#define M_TOT    (NBUCKETS * NB)                  // 300,544 partials
#define SB       256                              // scan blocks
#define CH       ((M_TOT + SB - 1) / SB)

// ---------- CSR build (zero global atomics) ----------

__global__ void bucket_hist_kernel(const int* __restrict__ rows,
                                   int* __restrict__ partial, int n_edges) {
    __shared__ int h[NBUCKETS];
    for (int i = threadIdx.x; i < NBUCKETS; i += blockDim.x) h[i] = 0;
    __syncthreads();
    int stride = gridDim.x * blockDim.x;
    for (int e = blockIdx.x * blockDim.x + threadIdx.x; e < n_edges; e += stride)
        atomicAdd(&h[((unsigned)rows[e]) >> BSHIFT], 1);
    __syncthreads();
    for (int i = threadIdx.x; i < NBUCKETS; i += blockDim.x)
        partial[blockIdx.x * NBUCKETS + i] = h[i];
}

// Logical L = bucket*NB + block; physical = block*NBUCKETS + bucket.
__device__ __forceinline__ int phys_idx(int L) {
    return (L & (NB - 1)) * NBUCKETS + (L >> NBSHIFT);
}

__global__ void scanB1_kernel(const int* __restrict__ partial,
                              int* __restrict__ psum) {
    __shared__ int s[256];
    int tid = threadIdx.x;
    int c0 = blockIdx.x * CH;
    int c1 = min(M_TOT, c0 + CH);
    int sum = 0;
    for (int L = c0 + tid; L < c1; L += 256) sum += partial[phys_idx(L)];
    s[tid] = sum;
    __syncthreads();
    for (int off = 128; off > 0; off >>= 1) {
        if (tid < off) s[tid] += s[tid + off];
        __syncthreads();
    }
    if (tid == 0) psum[blockIdx.x] = s[0];
}

__global__ void scanB2_kernel(int* __restrict__ psum) {
    __shared__ int s[SB];
    int tid = threadIdx.x;
    s[tid] = psum[tid];
    __syncthreads();
    for (int off = 1; off < SB; off <<= 1) {
        int v = (tid >= off) ? s[tid - off] : 0;
        __syncthreads();
        s[tid] += v;
        __syncthreads();
    }
    psum[tid] = tid ? s[tid - 1] : 0;
}

__global__ void scanB3_kernel(const int* __restrict__ partial,
                              const int* __restrict__ psum,
                              int* __restrict__ offs) {
    __shared__ int tile[256];
    __shared__ int carry;
    int tid = threadIdx.x;
    int c0 = blockIdx.x * CH;
    int c1 = min(M_TOT, c0 + CH);
    if (tid == 0) carry = psum[blockIdx.x];
    __syncthreads();
    for (int base = c0; base < c1; base += 256) {
        int L = base + tid;
        int v = (L < c1) ? partial[phys_idx(L)] : 0;
        tile[tid] = v;
        __syncthreads();
        for (int off = 1; off < 256; off <<= 1) {
            int t = (tid >= off) ? tile[tid - off] : 0;
            __syncthreads();
            tile[tid] += t;
            __syncthreads();
        }
        if (L < c1) offs[L] = carry + tile[tid] - v;
        __syncthreads();
        if (tid == 255) carry += tile[255];
        __syncthreads();
    }
}

// Bin edges into 512-row buckets at exact positions; LDS-only atomics.
__global__ void scatter1_kernel(const int* __restrict__ rows,
                                const int* __restrict__ cols,
                                const float* __restrict__ vals,
                                const int* __restrict__ offs,
                                int2* __restrict__ bkt_buf, int n_edges) {
    __shared__ int lpos[NBUCKETS];
    for (int i = threadIdx.x; i < NBUCKETS; i += blockDim.x)
        lpos[i] = offs[i * NB + blockIdx.x];
    __syncthreads();
    int stride = gridDim.x * blockDim.x;
    for (int e = blockIdx.x * blockDim.x + threadIdx.x; e < n_edges; e += stride) {
        int r = rows[e];
        int b = ((unsigned)r) >> BSHIFT;
        int pos = atomicAdd(&lpos[b], 1);
        int2 p;
        p.x = cols[e] | ((r & (BROWS - 1)) << 19);
        p.y = __float_as_int(vals[e]);
        bkt_buf[pos] = p;
    }
}

// One block per 512-row bucket: LDS row hist, 2-elem/thread scan, emit
// row_ptr directly, place edges into the bucket's contiguous CSR span.
__global__ void scatter2_kernel(const int2* __restrict__ bkt_buf,
                                const int* __restrict__ offs,
                                int* __restrict__ row_ptr,
                                int2* __restrict__ csr_cv, int n_edges) {
    __shared__ int lcnt[BROWS];
    __shared__ int lptr[BROWS];
    __shared__ int lfill[BROWS];
    __shared__ int s[256];
    int b = blockIdx.x;
    int t = threadIdx.x;
    int e0 = offs[b * NB];
    int e1 = (b == NBUCKETS - 1) ? n_edges : offs[(b + 1) * NB];
    lcnt[t] = 0;          lcnt[t + 256] = 0;
    lfill[t] = 0;         lfill[t + 256] = 0;
    __syncthreads();
    for (int e = e0 + t; e < e1; e += blockDim.x)
        atomicAdd(&lcnt[((unsigned)bkt_buf[e].x) >> 19], 1);
    __syncthreads();
    s[t] = lcnt[2 * t] + lcnt[2 * t + 1];
    __syncthreads();
    for (int off = 1; off < 256; off <<= 1) {
        int v = (t >= off) ? s[t - off] : 0;
        __syncthreads();
        s[t] += v;                       // inclusive over pairs
        __syncthreads();
    }
    int base = e0 + (t ? s[t - 1] : 0);
    int rbase = b << BSHIFT;
    int p_even = base;
    int p_odd  = base + lcnt[2 * t];
    lptr[2 * t]     = p_even;
    lptr[2 * t + 1] = p_odd;
    if (rbase + 2 * t     < N_NODES) row_ptr[rbase + 2 * t]     = p_even;
    if (rbase + 2 * t + 1 < N_NODES) row_ptr[rbase + 2 * t + 1] = p_odd;
    if (b == NBUCKETS - 1 && t == 0) row_ptr[N_NODES] = n_edges;
    __syncthreads();
    for (int e = e0 + t; e < e1; e += blockDim.x) {
        int2 p = bkt_buf[e];
        int delta = ((unsigned)p.x) >> 19;
        int pos = lptr[delta] + atomicAdd(&lfill[delta], 1);
        int2 cv;
        cv.x = p.x & COLMASK;
        cv.y = p.y;
        csr_cv[pos] = cv;
    }
}

// ---------- h0 = fp16(concat(user, item, topic)) ----------
__global__ void concat_f16_kernel(const float* __restrict__ uemb,
                                  const float* __restrict__ iemb,
                                  const float* __restrict__ temb,
                                  ushort* __restrict__ h0) {
    int g = blockIdx.x * blockDim.x + threadIdx.x;     // group of 4 elems
    long base = (long)g * 4;
    if (base >= (long)N_NODES * DIM) return;
    const float* src;
    long off;
    if (base < (long)N_USERS * DIM)                 { src = uemb; off = base; }
    else if (base < (long)(N_USERS + N_ITEMS) * DIM){ src = iemb; off = base - (long)N_USERS * DIM; }
    else                                            { src = temb; off = base - (long)(N_USERS + N_ITEMS) * DIM; }
    float4 v = *(const float4*)(src + off);
    __half2 a = __floats2half2_rn(v.x, v.y);
    __half2 b = __floats2half2_rn(v.z, v.w);
    uint2 o;
    o.x = *(unsigned*)&a;
    o.y = *(unsigned*)&b;
    ((uint2*)h0)[g] = o;
}

// ---------- SpMV: 1 wave/row, 16 edges in flight, fp16 rows, fp32 math ----
__device__ __forceinline__ float4 load_half4(const ushort* __restrict__ h,
                                             int row, int l16, float w,
                                             float4 acc) {
    uint2 r = ((const uint2*)(h + (size_t)row * DIM))[l16];
    float2 f01 = __half22float2(*(__half2*)&r.x);
    float2 f23 = __half22float2(*(__half2*)&r.y);
    acc.x += w * f01.x;
    acc.y += w * f01.y;
    acc.z += w * f23.x;
    acc.w += w * f23.y;
    return acc;
}

__global__ void spmv_csr_kernel(const int* __restrict__ row_ptr,
                                const int2* __restrict__ csr_cv,
                                const ushort* __restrict__ h_src,
                                ushort* __restrict__ h_dst) {
    int wid  = (int)(((long)blockIdx.x * blockDim.x + threadIdx.x) >> 6);
    int lane = threadIdx.x & 63;
    if (wid >= N_NODES) return;
    int g   = lane >> 4;
    int l16 = lane & 15;
    int p0 = row_ptr[wid];
    int p1 = row_ptr[wid + 1];
    float4 acc = make_float4(0.f, 0.f, 0.f, 0.f);
    for (int base = p0; base < p1; base += 16) {
        int e0 = base + g, e1 = base + 4 + g, e2 = base + 8 + g, e3 = base + 12 + g;
        bool k0 = e0 < p1, k1 = e1 < p1, k2 = e2 < p1, k3 = e3 < p1;
        int2 cv0 = csr_cv[k0 ? e0 : p0];
        int2 cv1 = csr_cv[k1 ? e1 : p0];
        int2 cv2 = csr_cv[k2 ? e2 : p0];
        int2 cv3 = csr_cv[k3 ? e3 : p0];
        float v0 = k0 ? __int_as_float(cv0.y) : 0.f;
        float v1 = k1 ? __int_as_float(cv1.y) : 0.f;
        float v2 = k2 ? __int_as_float(cv2.y) : 0.f;
        float v3 = k3 ? __int_as_float(cv3.y) : 0.f;
        acc = load_half4(h_src, cv0.x, l16, v0, acc);
        acc = load_half4(h_src, cv1.x, l16, v1, acc);
        acc = load_half4(h_src, cv2.x, l16, v2, acc);
        acc = load_half4(h_src, cv3.x, l16, v3, acc);
    }
    acc.x += __shfl_xor(acc.x, 16, 64);  acc.x += __shfl_xor(acc.x, 32, 64);
    acc.y += __shfl_xor(acc.y, 16, 64);  acc.y += __shfl_xor(acc.y, 32, 64);
    acc.z += __shfl_xor(acc.z, 16, 64);  acc.z += __shfl_xor(acc.z, 32, 64);
    acc.w += __shfl_xor(acc.w, 16, 64);  acc.w += __shfl_xor(acc.w, 32, 64);
    if (lane < 16) {
        __half2 a = __floats2half2_rn(acc.x, acc.y);
        __half2 b = __floats2half2_rn(acc.z, acc.w);
        uint2 o;
        o.x = *(unsigned*)&a;
        o.y = *(unsigned*)&b;
        ((uint2*)(h_dst + (size_t)wid * DIM))[l16] = o;
    }
}

// ---------- batch-row accumulation (fp32 acc) + readout ----------

__global__ void gather_add_kernel(const ushort* __restrict__ h,
                                  const int* __restrict__ users,
                                  const int* __restrict__ items,
                                  float* __restrict__ u_acc,
                                  float* __restrict__ it_acc,
                                  int B, int first) {
    int gid  = blockIdx.x * blockDim.x + threadIdx.x;
    int b    = gid >> 4;
    int lane = gid & 15;
    if (b >= B) return;
    int u  = users[b];
    int it = N_USERS + items[b];
    uint2 ur = ((const uint2*)(h + (size_t)u  * DIM))[lane];
    uint2 ir = ((const uint2*)(h + (size_t)it * DIM))[lane];
    float2 u01 = __half22float2(*(__half2*)&ur.x);
    float2 u23 = __half22float2(*(__half2*)&ur.y);
    float2 i01 = __half22float2(*(__half2*)&ir.x);
    float2 i23 = __half22float2(*(__half2*)&ir.y);
    float4* up = (float4*)(u_acc  + (size_t)b * DIM) + lane;
    float4* ip = (float4*)(it_acc + (size_t)b * DIM) + lane;
    if (first) {
        *up = make_float4(u01.x, u01.y, u23.x, u23.y);
        *ip = make_float4(i01.x, i01.y, i23.x, i23.y);
    } else {
        float4 a = *up;
        a.x += u01.x; a.y += u01.y; a.z += u23.x; a.w += u23.y;
        *up = a;
        float4 c = *ip;
        c.x += i01.x; c.y += i01.y; c.z += i23.x; c.w += i23.y;
        *ip = c;
    }
}

__global__ void dot_kernel(const float* __restrict__ u_acc,
                           const float* __restrict__ it_acc,
                           float* __restrict__ out, int B) {
    int gid  = blockIdx.x * blockDim.x + threadIdx.x;
    int b    = gid >> 6;
    int lane = gid & 63;
    if (b >= B) return;
    float p = u_acc[(size_t)b * DIM + lane] * it_acc[(size_t)b * DIM + lane];
    #pragma unroll
    for (int off = 32; off > 0; off >>= 1)
        p += __shfl_down(p, off, 64);
    if (lane == 0) out[b] = p * (1.0f / 16.0f);
}

extern "C" void kernel_launch(void* const* d_in, const int* in_sizes, int n_in,
                              void* d_out, int out_size, void* d_ws, size_t ws_size,
                              hipStream_t stream) {
    const int*   users = (const int*)d_in[0];
    const int*   items = (const int*)d_in[1];
    const int*   erows = (const int*)d_in[2];
    const int*   ecols = (const int*)d_in[3];
    const float* evals = (const float*)d_in[4];
    const float* uemb  = (const float*)d_in[5];
    const float* iemb  = (const float*)d_in[6];
    const float* temb  = (const float*)d_in[7];
    float* out = (float*)d_out;

    const int n_edges = in_sizes[2];
    const int B       = in_sizes[0];

    const size_t h2bytes = (((size_t)N_NODES * DIM * 2 + 255) / 256) * 256;  // 38.4 MB
    const size_t abytes  = (size_t)B * DIM * sizeof(float);                  // 4.2 MB
    const size_t rpbytes = (((size_t)(N_NODES + 1) * 4 + 255) / 256) * 256;
    const size_t cvbytes = (size_t)n_edges * 8;                              // 40 MB
    const size_t mbytes  = (((size_t)M_TOT * 4 + 255) / 256) * 256;          // 1.2 MB

    char* ws = (char*)d_ws;
    size_t off = 0;
    ushort* hA      = (ushort*)(ws + off); off += h2bytes;
    ushort* hB      = (ushort*)(ws + off); off += h2bytes;
    float*  u_acc   = (float*) (ws + off); off += abytes;
    float*  it_acc  = (float*) (ws + off); off += abytes;
    int*    row_ptr = (int*)   (ws + off); off += rpbytes;
    int2*   csr_cv  = (int2*)  (ws + off); off += cvbytes;
    int2*   bkt_buf = (int2*)  (ws + off); off += cvbytes;
    int*    partial = (int*)   (ws + off); off += mbytes;
    int*    offs    = (int*)   (ws + off); off += mbytes;
    int*    psum    = (int*)   (ws + off); off += 4096;   // ~168 MB total

    dim3 blk(256);

    // ---- CSR build: zero global atomics ----
    bucket_hist_kernel<<<NB, blk, 0, stream>>>(erows, partial, n_edges);
    scanB1_kernel<<<SB, blk, 0, stream>>>(partial, psum);
    scanB2_kernel<<<1,  SB,  0, stream>>>(psum);
    scanB3_kernel<<<SB, blk, 0, stream>>>(partial, psum, offs);
    scatter1_kernel<<<NB, blk, 0, stream>>>(erows, ecols, evals, offs, bkt_buf, n_edges);
    scatter2_kernel<<<NBUCKETS, blk, 0, stream>>>(bkt_buf, offs, row_ptr, csr_cv, n_edges);

    // ---- h0 ----
    const long n4 = (long)N_NODES * DIM / 4;
    concat_f16_kernel<<<(int)((n4 + 255) / 256), blk, 0, stream>>>(uemb, iemb, temb, hA);

    const int gblocks = (B * 16 + 255) / 256;
    gather_add_kernel<<<gblocks, blk, 0, stream>>>(hA, users, items, u_acc, it_acc, B, 1);

    const int sblocks = (int)(((long)N_NODES * 64 + 255) / 256);
    ushort* src = hA;
    ushort* dst = hB;
    for (int l = 0; l < 3; ++l) {
        spmv_csr_kernel<<<sblocks, blk, 0, stream>>>(row_ptr, csr_cv, src, dst);
        gather_add_kernel<<<gblocks, blk, 0, stream>>>(dst, users, items, u_acc, it_acc, B, 0);
        ushort* t = src; src = dst; dst = t;
    }

    dot_kernel<<<(B * 64 + 255) / 256, blk, 0, stream>>>(u_acc, it_acc, out, B);
}

// Round 8
// 706.940 us; speedup vs baseline: 2.1870x; 1.0220x over previous
//
#include <hip/hip_runtime.h>
#include <hip/hip_fp16.h>

#define N_USERS  200000
#define N_ITEMS  100000
#define N_TOPICS 100
#define N_NODES  (N_USERS + N_ITEMS + N_TOPICS)
#define DIM      64
#define BSHIFT   9                                // 512 rows per bucket
#define BROWS    (1 << BSHIFT)
#define NBUCKETS ((N_NODES + BROWS - 1) >> BSHIFT)   // 587
#define COLMASK  0x7FFFF                          // 19 bits (N_NODES < 2^19)
#define NB       512                              // binning blocks
#define NBSHIFT  9
#define M_TOT    (NBUCKETS * NB)                  // 300,544 partials
#define SB       256                              // scan blocks
#define CH       ((M_TOT + SB - 1) / SB)

// ---------- CSR build (zero global atomics) ----------

__global__ void bucket_hist_kernel(const int* __restrict__ rows,
                                   int* __restrict__ partial, int n_edges) {
    __shared__ int h[NBUCKETS];
    for (int i = threadIdx.x; i < NBUCKETS; i += blockDim.x) h[i] = 0;
    __syncthreads();
    int stride = gridDim.x * blockDim.x;
    for (int e = blockIdx.x * blockDim.x + threadIdx.x; e < n_edges; e += stride)
        atomicAdd(&h[((unsigned)rows[e]) >> BSHIFT], 1);
    __syncthreads();
    for (int i = threadIdx.x; i < NBUCKETS; i += blockDim.x)
        partial[blockIdx.x * NBUCKETS + i] = h[i];
}

// Logical L = bucket*NB + block; physical = block*NBUCKETS + bucket.
__device__ __forceinline__ int phys_idx(int L) {
    return (L & (NB - 1)) * NBUCKETS + (L >> NBSHIFT);
}

__global__ void scanB1_kernel(const int* __restrict__ partial,
                              int* __restrict__ psum) {
    __shared__ int s[256];
    int tid = threadIdx.x;
    int c0 = blockIdx.x * CH;
    int c1 = min(M_TOT, c0 + CH);
    int sum = 0;
    for (int L = c0 + tid; L < c1; L += 256) sum += partial[phys_idx(L)];
    s[tid] = sum;
    __syncthreads();
    for (int off = 128; off > 0; off >>= 1) {
        if (tid < off) s[tid] += s[tid + off];
        __syncthreads();
    }
    if (tid == 0) psum[blockIdx.x] = s[0];
}

__global__ void scanB2_kernel(int* __restrict__ psum) {
    __shared__ int s[SB];
    int tid = threadIdx.x;
    s[tid] = psum[tid];
    __syncthreads();
    for (int off = 1; off < SB; off <<= 1) {
        int v = (tid >= off) ? s[tid - off] : 0;
        __syncthreads();
        s[tid] += v;
        __syncthreads();
    }
    psum[tid] = tid ? s[tid - 1] : 0;
}

__global__ void scanB3_kernel(const int* __restrict__ partial,
                              const int* __restrict__ psum,
                              int* __restrict__ offs) {
    __shared__ int tile[256];
    __shared__ int carry;
    int tid = threadIdx.x;
    int c0 = blockIdx.x * CH;
    int c1 = min(M_TOT, c0 + CH);
    if (tid == 0) carry = psum[blockIdx.x];
    __syncthreads();
    for (int base = c0; base < c1; base += 256) {
        int L = base + tid;
        int v = (L < c1) ? partial[phys_idx(L)] : 0;
        tile[tid] = v;
        __syncthreads();
        for (int off = 1; off < 256; off <<= 1) {
            int t = (tid >= off) ? tile[tid - off] : 0;
            __syncthreads();
            tile[tid] += t;
            __syncthreads();
        }
        if (L < c1) offs[L] = carry + tile[tid] - v;
        __syncthreads();
        if (tid == 255) carry += tile[255];
        __syncthreads();
    }
}

// Bin edges into 512-row buckets at exact positions; LDS-only atomics.
__global__ void scatter1_kernel(const int* __restrict__ rows,
                                const int* __restrict__ cols,
                                const float* __restrict__ vals,
                                const int* __restrict__ offs,
                                int2* __restrict__ bkt_buf, int n_edges) {
    __shared__ int lpos[NBUCKETS];
    for (int i = threadIdx.x; i < NBUCKETS; i += blockDim.x)
        lpos[i] = offs[i * NB + blockIdx.x];
    __syncthreads();
    int stride = gridDim.x * blockDim.x;
    for (int e = blockIdx.x * blockDim.x + threadIdx.x; e < n_edges; e += stride) {
        int r = rows[e];
        int b = ((unsigned)r) >> BSHIFT;
        int pos = atomicAdd(&lpos[b], 1);
        int2 p;
        p.x = cols[e] | ((r & (BROWS - 1)) << 19);
        p.y = __float_as_int(vals[e]);
        bkt_buf[pos] = p;
    }
}

// One block per 512-row bucket: LDS row hist, 2-elem/thread scan, emit
// row_ptr directly, place edges into the bucket's contiguous CSR span.
__global__ void scatter2_kernel(const int2* __restrict__ bkt_buf,
                                const int* __restrict__ offs,
                                int* __restrict__ row_ptr,
                                int2* __restrict__ csr_cv, int n_edges) {
    __shared__ int lcnt[BROWS];
    __shared__ int lptr[BROWS];
    __shared__ int lfill[BROWS];
    __shared__ int s[256];
    int b = blockIdx.x;
    int t = threadIdx.x;
    int e0 = offs[b * NB];
    int e1 = (b == NBUCKETS - 1) ? n_edges : offs[(b + 1) * NB];
    lcnt[t] = 0;          lcnt[t + 256] = 0;
    lfill[t] = 0;         lfill[t + 256] = 0;
    __syncthreads();
    for (int e = e0 + t; e < e1; e += blockDim.x)
        atomicAdd(&lcnt[((unsigned)bkt_buf[e].x) >> 19], 1);
    __syncthreads();
    s[t] = lcnt[2 * t] + lcnt[2 * t + 1];
    __syncthreads();
    for (int off = 1; off < 256; off <<= 1) {
        int v = (t >= off) ? s[t - off] : 0;
        __syncthreads();
        s[t] += v;                       // inclusive over pairs
        __syncthreads();
    }
    int base = e0 + (t ? s[t - 1] : 0);
    int rbase = b << BSHIFT;
    int p_even = base;
    int p_odd  = base + lcnt[2 * t];
    lptr[2 * t]     = p_even;
    lptr[2 * t + 1] = p_odd;
    if (rbase + 2 * t     < N_NODES) row_ptr[rbase + 2 * t]     = p_even;
    if (rbase + 2 * t + 1 < N_NODES) row_ptr[rbase + 2 * t + 1] = p_odd;
    if (b == NBUCKETS - 1 && t == 0) row_ptr[N_NODES] = n_edges;
    __syncthreads();
    for (int e = e0 + t; e < e1; e += blockDim.x) {
        int2 p = bkt_buf[e];
        int delta = ((unsigned)p.x) >> 19;
        int pos = lptr[delta] + atomicAdd(&lfill[delta], 1);
        int2 cv;
        cv.x = p.x & COLMASK;
        cv.y = p.y;
        csr_cv[pos] = cv;
    }
}

// ---------- h0 = fp16(concat(user, item, topic)) ----------
__global__ void concat_f16_kernel(const float* __restrict__ uemb,
                                  const float* __restrict__ iemb,
                                  const float* __restrict__ temb,
                                  ushort* __restrict__ h0) {
    int g = blockIdx.x * blockDim.x + threadIdx.x;     // group of 4 elems
    long base = (long)g * 4;
    if (base >= (long)N_NODES * DIM) return;
    const float* src;
    long off;
    if (base < (long)N_USERS * DIM)                 { src = uemb; off = base; }
    else if (base < (long)(N_USERS + N_ITEMS) * DIM){ src = iemb; off = base - (long)N_USERS * DIM; }
    else                                            { src = temb; off = base - (long)(N_USERS + N_ITEMS) * DIM; }
    float4 v = *(const float4*)(src + off);
    __half2 a = __floats2half2_rn(v.x, v.y);
    __half2 b = __floats2half2_rn(v.z, v.w);
    uint2 o;
    o.x = *(unsigned*)&a;
    o.y = *(unsigned*)&b;
    ((uint2*)h0)[g] = o;
}

// ---------- SpMV: 1 wave/row, 16 edges in flight, fp16 rows, fp32 math ----
// fmaf(half2float(h), w, acc) pattern-matches to v_fma_mix_f32 (fp16 src via
// op_sel, fp32 MAC): 4 VALU per 4 elems instead of 4 cvt + 4 fma.
__device__ __forceinline__ float4 fma_mix4(const ushort* __restrict__ h,
                                           int row, int l16, float w,
                                           float4 acc) {
    uint2 r = ((const uint2*)(h + (size_t)row * DIM))[l16];
    __half2 h01 = *(__half2*)&r.x;
    __half2 h23 = *(__half2*)&r.y;
    acc.x = __builtin_fmaf(__half2float(__low2half(h01)),  w, acc.x);
    acc.y = __builtin_fmaf(__half2float(__high2half(h01)), w, acc.y);
    acc.z = __builtin_fmaf(__half2float(__low2half(h23)),  w, acc.z);
    acc.w = __builtin_fmaf(__half2float(__high2half(h23)), w, acc.w);
    return acc;
}

__global__ void spmv_csr_kernel(const int* __restrict__ row_ptr,
                                const int2* __restrict__ csr_cv,
                                const ushort* __restrict__ h_src,
                                ushort* __restrict__ h_dst) {
    int wid  = (int)(((long)blockIdx.x * blockDim.x + threadIdx.x) >> 6);
    int lane = threadIdx.x & 63;
    if (wid >= N_NODES) return;
    int g   = lane >> 4;
    int l16 = lane & 15;
    int p0 = row_ptr[wid];
    int p1 = row_ptr[wid + 1];
    float4 acc = make_float4(0.f, 0.f, 0.f, 0.f);
    for (int base = p0; base < p1; base += 16) {
        int e0 = base + g, e1 = base + 4 + g, e2 = base + 8 + g, e3 = base + 12 + g;
        bool k0 = e0 < p1, k1 = e1 < p1, k2 = e2 < p1, k3 = e3 < p1;
        int2 cv0 = csr_cv[k0 ? e0 : p0];
        int2 cv1 = csr_cv[k1 ? e1 : p0];
        int2 cv2 = csr_cv[k2 ? e2 : p0];
        int2 cv3 = csr_cv[k3 ? e3 : p0];
        float v0 = k0 ? __int_as_float(cv0.y) : 0.f;
        float v1 = k1 ? __int_as_float(cv1.y) : 0.f;
        float v2 = k2 ? __int_as_float(cv2.y) : 0.f;
        float v3 = k3 ? __int_as_float(cv3.y) : 0.f;
        acc = fma_mix4(h_src, cv0.x, l16, v0, acc);
        acc = fma_mix4(h_src, cv1.x, l16, v1, acc);
        acc = fma_mix4(h_src, cv2.x, l16, v2, acc);
        acc = fma_mix4(h_src, cv3.x, l16, v3, acc);
    }
    acc.x += __shfl_xor(acc.x, 16, 64);  acc.x += __shfl_xor(acc.x, 32, 64);
    acc.y += __shfl_xor(acc.y, 16, 64);  acc.y += __shfl_xor(acc.y, 32, 64);
    acc.z += __shfl_xor(acc.z, 16, 64);  acc.z += __shfl_xor(acc.z, 32, 64);
    acc.w += __shfl_xor(acc.w, 16, 64);  acc.w += __shfl_xor(acc.w, 32, 64);
    if (lane < 16) {
        __half2 a = __floats2half2_rn(acc.x, acc.y);
        __half2 b = __floats2half2_rn(acc.z, acc.w);
        uint2 o;
        o.x = *(unsigned*)&a;
        o.y = *(unsigned*)&b;
        ((uint2*)(h_dst + (size_t)wid * DIM))[l16] = o;
    }
}

// ---------- batch-row accumulation (fp32 acc) + readout ----------

__global__ void gather_add_kernel(const ushort* __restrict__ h,
                                  const int* __restrict__ users,
                                  const int* __restrict__ items,
                                  float* __restrict__ u_acc,
                                  float* __restrict__ it_acc,
                                  int B, int first) {
    int gid  = blockIdx.x * blockDim.x + threadIdx.x;
    int b    = gid >> 4;
    int lane = gid & 15;
    if (b >= B) return;
    int u  = users[b];
    int it = N_USERS + items[b];
    uint2 ur = ((const uint2*)(h + (size_t)u  * DIM))[lane];
    uint2 ir = ((const uint2*)(h + (size_t)it * DIM))[lane];
    float2 u01 = __half22float2(*(__half2*)&ur.x);
    float2 u23 = __half22float2(*(__half2*)&ur.y);
    float2 i01 = __half22float2(*(__half2*)&ir.x);
    float2 i23 = __half22float2(*(__half2*)&ir.y);
    float4* up = (float4*)(u_acc  + (size_t)b * DIM) + lane;
    float4* ip = (float4*)(it_acc + (size_t)b * DIM) + lane;
    if (first) {
        *up = make_float4(u01.x, u01.y, u23.x, u23.y);
        *ip = make_float4(i01.x, i01.y, i23.x, i23.y);
    } else {
        float4 a = *up;
        a.x += u01.x; a.y += u01.y; a.z += u23.x; a.w += u23.y;
        *up = a;
        float4 c = *ip;
        c.x += i01.x; c.y += i01.y; c.z += i23.x; c.w += i23.y;
        *ip = c;
    }
}

__global__ void dot_kernel(const float* __restrict__ u_acc,
                           const float* __restrict__ it_acc,
                           float* __restrict__ out, int B) {
    int gid  = blockIdx.x * blockDim.x + threadIdx.x;
    int b    = gid >> 6;
    int lane = gid & 63;
    if (b >= B) return;
    float p = u_acc[(size_t)b * DIM + lane] * it_acc[(size_t)b * DIM + lane];
    #pragma unroll
    for (int off = 32; off > 0; off >>= 1)
        p += __shfl_down(p, off, 64);
    if (lane == 0) out[b] = p * (1.0f / 16.0f);
}

extern "C" void kernel_launch(void* const* d_in, const int* in_sizes, int n_in,
                              void* d_out, int out_size, void* d_ws, size_t ws_size,
                              hipStream_t stream) {
    const int*   users = (const int*)d_in[0];
    const int*   items = (const int*)d_in[1];
    const int*   erows = (const int*)d_in[2];
    const int*   ecols = (const int*)d_in[3];
    const float* evals = (const float*)d_in[4];
    const float* uemb  = (const float*)d_in[5];
    const float* iemb  = (const float*)d_in[6];
    const float* temb  = (const float*)d_in[7];
    float* out = (float*)d_out;

    const int n_edges = in_sizes[2];
    const int B       = in_sizes[0];

    const size_t h2bytes = (((size_t)N_NODES * DIM * 2 + 255) / 256) * 256;  // 38.4 MB
    const size_t abytes  = (size_t)B * DIM * sizeof(float);                  // 4.2 MB
    const size_t rpbytes = (((size_t)(N_NODES + 1) * 4 + 255) / 256) * 256;
    const size_t cvbytes = (size_t)n_edges * 8;                              // 40 MB
    const size_t mbytes  = (((size_t)M_TOT * 4 + 255) / 256) * 256;          // 1.2 MB

    char* ws = (char*)d_ws;
    size_t off = 0;
    ushort* hA      = (ushort*)(ws + off); off += h2bytes;
    ushort* hB      = (ushort*)(ws + off); off += h2bytes;
    float*  u_acc   = (float*) (ws + off); off += abytes;
    float*  it_acc  = (float*) (ws + off); off += abytes;
    int*    row_ptr = (int*)   (ws + off); off += rpbytes;
    int2*   csr_cv  = (int2*)  (ws + off); off += cvbytes;
    int2*   bkt_buf = (int2*)  (ws + off); off += cvbytes;
    int*    partial = (int*)   (ws + off); off += mbytes;
    int*    offs    = (int*)   (ws + off); off += mbytes;
    int*    psum    = (int*)   (ws + off); off += 4096;   // ~168 MB total

    dim3 blk(256);

    // ---- CSR build: zero global atomics ----
    bucket_hist_kernel<<<NB, blk, 0, stream>>>(erows, partial, n_edges);
    scanB1_kernel<<<SB, blk, 0, stream>>>(partial, psum);
    scanB2_kernel<<<1,  SB,  0, stream>>>(psum);
    scanB3_kernel<<<SB, blk, 0, stream>>>(partial, psum, offs);
    scatter1_kernel<<<NB, blk, 0, stream>>>(erows, ecols, evals, offs, bkt_buf, n_edges);
    scatter2_kernel<<<NBUCKETS, blk, 0, stream>>>(bkt_buf, offs, row_ptr, csr_cv, n_edges);

    // ---- h0 ----
    const long n4 = (long)N_NODES * DIM / 4;
    concat_f16_kernel<<<(int)((n4 + 255) / 256), blk, 0, stream>>>(uemb, iemb, temb, hA);

    const int gblocks = (B * 16 + 255) / 256;
    gather_add_kernel<<<gblocks, blk, 0, stream>>>(hA, users, items, u_acc, it_acc, B, 1);

    const int sblocks = (int)(((long)N_NODES * 64 + 255) / 256);
    ushort* src = hA;
    ushort* dst = hB;
    for (int l = 0; l < 3; ++l) {
        spmv_csr_kernel<<<sblocks, blk, 0, stream>>>(row_ptr, csr_cv, src, dst);
        gather_add_kernel<<<gblocks, blk, 0, stream>>>(dst, users, items, u_acc, it_acc, B, 0);
        ushort* t = src; src = dst; dst = t;
    }

    dot_kernel<<<(B * 64 + 255) / 256, blk, 0, stream>>>(u_acc, it_acc, out, B);
}

// Round 9
// 694.459 us; speedup vs baseline: 2.2263x; 1.0180x over previous
//
#include <hip/hip_runtime.h>
#include <hip/hip_fp16.h>

#define N_USERS  200000
#define N_ITEMS  100000
#define N_TOPICS 100
#define N_NODES  (N_USERS + N_ITEMS + N_TOPICS)
#define DIM      64
#define BSHIFT   9                                // 512 rows per bucket
#define BROWS    (1 << BSHIFT)
#define NBUCKETS ((N_NODES + BROWS - 1) >> BSHIFT)   // 587
#define COLMASK  0x7FFFF                          // 19 bits (N_NODES < 2^19)
#define NB       512                              // binning blocks
#define NBSHIFT  9
#define M_TOT    (NBUCKETS * NB)                  // 300,544 partials
#define SB       256                              // scan blocks
#define CH       ((M_TOT + SB - 1) / SB)

// ---------- CSR build (zero global atomics) ----------

__global__ void bucket_hist_kernel(const int* __restrict__ rows,
                                   int* __restrict__ partial, int n_edges) {
    __shared__ int h[NBUCKETS];
    for (int i = threadIdx.x; i < NBUCKETS; i += blockDim.x) h[i] = 0;
    __syncthreads();
    int stride = gridDim.x * blockDim.x;
    for (int e = blockIdx.x * blockDim.x + threadIdx.x; e < n_edges; e += stride)
        atomicAdd(&h[((unsigned)rows[e]) >> BSHIFT], 1);
    __syncthreads();
    for (int i = threadIdx.x; i < NBUCKETS; i += blockDim.x)
        partial[blockIdx.x * NBUCKETS + i] = h[i];
}

// Logical L = bucket*NB + block; physical = block*NBUCKETS + bucket.
__device__ __forceinline__ int phys_idx(int L) {
    return (L & (NB - 1)) * NBUCKETS + (L >> NBSHIFT);
}

__global__ void scanB1_kernel(const int* __restrict__ partial,
                              int* __restrict__ psum) {
    __shared__ int s[256];
    int tid = threadIdx.x;
    int c0 = blockIdx.x * CH;
    int c1 = min(M_TOT, c0 + CH);
    int sum = 0;
    for (int L = c0 + tid; L < c1; L += 256) sum += partial[phys_idx(L)];
    s[tid] = sum;
    __syncthreads();
    for (int off = 128; off > 0; off >>= 1) {
        if (tid < off) s[tid] += s[tid + off];
        __syncthreads();
    }
    if (tid == 0) psum[blockIdx.x] = s[0];
}

__global__ void scanB2_kernel(int* __restrict__ psum) {
    __shared__ int s[SB];
    int tid = threadIdx.x;
    s[tid] = psum[tid];
    __syncthreads();
    for (int off = 1; off < SB; off <<= 1) {
        int v = (tid >= off) ? s[tid - off] : 0;
        __syncthreads();
        s[tid] += v;
        __syncthreads();
    }
    psum[tid] = tid ? s[tid - 1] : 0;
}

__global__ void scanB3_kernel(const int* __restrict__ partial,
                              const int* __restrict__ psum,
                              int* __restrict__ offs) {
    __shared__ int tile[256];
    __shared__ int carry;
    int tid = threadIdx.x;
    int c0 = blockIdx.x * CH;
    int c1 = min(M_TOT, c0 + CH);
    if (tid == 0) carry = psum[blockIdx.x];
    __syncthreads();
    for (int base = c0; base < c1; base += 256) {
        int L = base + tid;
        int v = (L < c1) ? partial[phys_idx(L)] : 0;
        tile[tid] = v;
        __syncthreads();
        for (int off = 1; off < 256; off <<= 1) {
            int t = (tid >= off) ? tile[tid - off] : 0;
            __syncthreads();
            tile[tid] += t;
            __syncthreads();
        }
        if (L < c1) offs[L] = carry + tile[tid] - v;
        __syncthreads();
        if (tid == 255) carry += tile[255];
        __syncthreads();
    }
}

// Bin edges into 512-row buckets at exact positions; LDS-only atomics.
__global__ void scatter1_kernel(const int* __restrict__ rows,
                                const int* __restrict__ cols,
                                const float* __restrict__ vals,
                                const int* __restrict__ offs,
                                int2* __restrict__ bkt_buf, int n_edges) {
    __shared__ int lpos[NBUCKETS];
    for (int i = threadIdx.x; i < NBUCKETS; i += blockDim.x)
        lpos[i] = offs[i * NB + blockIdx.x];
    __syncthreads();
    int stride = gridDim.x * blockDim.x;
    for (int e = blockIdx.x * blockDim.x + threadIdx.x; e < n_edges; e += stride) {
        int r = rows[e];
        int b = ((unsigned)r) >> BSHIFT;
        int pos = atomicAdd(&lpos[b], 1);
        int2 p;
        p.x = cols[e] | ((r & (BROWS - 1)) << 19);
        p.y = __float_as_int(vals[e]);
        bkt_buf[pos] = p;
    }
}

// One block per 512-row bucket: LDS row hist, 2-elem/thread scan, emit
// row_ptr directly, place edges into the bucket's contiguous CSR span.
__global__ void scatter2_kernel(const int2* __restrict__ bkt_buf,
                                const int* __restrict__ offs,
                                int* __restrict__ row_ptr,
                                int2* __restrict__ csr_cv, int n_edges) {
    __shared__ int lcnt[BROWS];
    __shared__ int lptr[BROWS];
    __shared__ int lfill[BROWS];
    __shared__ int s[256];
    int b = blockIdx.x;
    int t = threadIdx.x;
    int e0 = offs[b * NB];
    int e1 = (b == NBUCKETS - 1) ? n_edges : offs[(b + 1) * NB];
    lcnt[t] = 0;          lcnt[t + 256] = 0;
    lfill[t] = 0;         lfill[t + 256] = 0;
    __syncthreads();
    for (int e = e0 + t; e < e1; e += blockDim.x)
        atomicAdd(&lcnt[((unsigned)bkt_buf[e].x) >> 19], 1);
    __syncthreads();
    s[t] = lcnt[2 * t] + lcnt[2 * t + 1];
    __syncthreads();
    for (int off = 1; off < 256; off <<= 1) {
        int v = (t >= off) ? s[t - off] : 0;
        __syncthreads();
        s[t] += v;                       // inclusive over pairs
        __syncthreads();
    }
    int base = e0 + (t ? s[t - 1] : 0);
    int rbase = b << BSHIFT;
    int p_even = base;
    int p_odd  = base + lcnt[2 * t];
    lptr[2 * t]     = p_even;
    lptr[2 * t + 1] = p_odd;
    if (rbase + 2 * t     < N_NODES) row_ptr[rbase + 2 * t]     = p_even;
    if (rbase + 2 * t + 1 < N_NODES) row_ptr[rbase + 2 * t + 1] = p_odd;
    if (b == NBUCKETS - 1 && t == 0) row_ptr[N_NODES] = n_edges;
    __syncthreads();
    for (int e = e0 + t; e < e1; e += blockDim.x) {
        int2 p = bkt_buf[e];
        int delta = ((unsigned)p.x) >> 19;
        int pos = lptr[delta] + atomicAdd(&lfill[delta], 1);
        int2 cv;
        cv.x = p.x & COLMASK;
        cv.y = p.y;
        csr_cv[pos] = cv;
    }
}

// ---------- h0 = fp16(concat(user, item, topic)) ----------
__global__ void concat_f16_kernel(const float* __restrict__ uemb,
                                  const float* __restrict__ iemb,
                                  const float* __restrict__ temb,
                                  ushort* __restrict__ h0) {
    int g = blockIdx.x * blockDim.x + threadIdx.x;     // group of 4 elems
    long base = (long)g * 4;
    if (base >= (long)N_NODES * DIM) return;
    const float* src;
    long off;
    if (base < (long)N_USERS * DIM)                 { src = uemb; off = base; }
    else if (base < (long)(N_USERS + N_ITEMS) * DIM){ src = iemb; off = base - (long)N_USERS * DIM; }
    else                                            { src = temb; off = base - (long)(N_USERS + N_ITEMS) * DIM; }
    float4 v = *(const float4*)(src + off);
    __half2 a = __floats2half2_rn(v.x, v.y);
    __half2 b = __floats2half2_rn(v.z, v.w);
    uint2 o;
    o.x = *(unsigned*)&a;
    o.y = *(unsigned*)&b;
    ((uint2*)h0)[g] = o;
}

// ---------- SpMV: 4 rows/wave (1 per 16-lane group), 8 edges in flight ----
// fmaf(half2float(h), w, acc) lowers to v_fma_mix_f32 (fp16 src, fp32 MAC).
__device__ __forceinline__ float4 fma_mix4(const ushort* __restrict__ h,
                                           int row, int l16, float w,
                                           float4 acc) {
    uint2 r = ((const uint2*)(h + (size_t)row * DIM))[l16];
    __half2 h01 = *(__half2*)&r.x;
    __half2 h23 = *(__half2*)&r.y;
    acc.x = __builtin_fmaf(__half2float(__low2half(h01)),  w, acc.x);
    acc.y = __builtin_fmaf(__half2float(__high2half(h01)), w, acc.y);
    acc.z = __builtin_fmaf(__half2float(__low2half(h23)),  w, acc.z);
    acc.w = __builtin_fmaf(__half2float(__high2half(h23)), w, acc.w);
    return acc;
}

__global__ void spmv_csr_kernel(const int* __restrict__ row_ptr,
                                const int2* __restrict__ csr_cv,
                                const ushort* __restrict__ h_src,
                                ushort* __restrict__ h_dst) {
    int wave = (int)(((long)blockIdx.x * blockDim.x + threadIdx.x) >> 6);
    int lane = threadIdx.x & 63;
    int g    = lane >> 4;            // row slot within wave
    int l16  = lane & 15;            // float4/uint2 index within 64-dim row
    int r    = wave * 4 + g;
    int rc   = min(r, N_NODES - 1);
    int p0   = row_ptr[rc];
    int p1   = row_ptr[rc + 1];
    int len  = (r < N_NODES) ? (p1 - p0) : 0;
    // max row length across the wave's 4 groups (groups differ in lane bits 4-5)
    int m = max(len, __shfl_xor(len, 16, 64));
    m = max(m, __shfl_xor(m, 32, 64));
    float4 acc = make_float4(0.f, 0.f, 0.f, 0.f);
    for (int off = 0; off < m; off += 8) {
        int2 cv[8];
        #pragma unroll
        for (int j = 0; j < 8; ++j) {
            bool k = (off + j) < len;
            cv[j] = csr_cv[k ? (p0 + off + j) : p0];
            if (!k) cv[j].y = 0;              // zero weight for dummies
        }
        #pragma unroll
        for (int j = 0; j < 8; ++j)
            acc = fma_mix4(h_src, cv[j].x, l16, __int_as_float(cv[j].y), acc);
    }
    if (r < N_NODES) {
        __half2 a = __floats2half2_rn(acc.x, acc.y);
        __half2 b = __floats2half2_rn(acc.z, acc.w);
        uint2 o;
        o.x = *(unsigned*)&a;
        o.y = *(unsigned*)&b;
        ((uint2*)(h_dst + (size_t)r * DIM))[l16] = o;
    }
}

// ---------- batch-row accumulation (fp32 acc) + readout ----------

__global__ void gather_add_kernel(const ushort* __restrict__ h,
                                  const int* __restrict__ users,
                                  const int* __restrict__ items,
                                  float* __restrict__ u_acc,
                                  float* __restrict__ it_acc,
                                  int B, int first) {
    int gid  = blockIdx.x * blockDim.x + threadIdx.x;
    int b    = gid >> 4;
    int lane = gid & 15;
    if (b >= B) return;
    int u  = users[b];
    int it = N_USERS + items[b];
    uint2 ur = ((const uint2*)(h + (size_t)u  * DIM))[lane];
    uint2 ir = ((const uint2*)(h + (size_t)it * DIM))[lane];
    float2 u01 = __half22float2(*(__half2*)&ur.x);
    float2 u23 = __half22float2(*(__half2*)&ur.y);
    float2 i01 = __half22float2(*(__half2*)&ir.x);
    float2 i23 = __half22float2(*(__half2*)&ir.y);
    float4* up = (float4*)(u_acc  + (size_t)b * DIM) + lane;
    float4* ip = (float4*)(it_acc + (size_t)b * DIM) + lane;
    if (first) {
        *up = make_float4(u01.x, u01.y, u23.x, u23.y);
        *ip = make_float4(i01.x, i01.y, i23.x, i23.y);
    } else {
        float4 a = *up;
        a.x += u01.x; a.y += u01.y; a.z += u23.x; a.w += u23.y;
        *up = a;
        float4 c = *ip;
        c.x += i01.x; c.y += i01.y; c.z += i23.x; c.w += i23.y;
        *ip = c;
    }
}

// Final layer fused: out[b] = dot64(u_acc[b] + h3[u], it_acc[b] + h3[it]) / 16.
__global__ void dot_fused_kernel(const ushort* __restrict__ h3,
                                 const float* __restrict__ u_acc,
                                 const float* __restrict__ it_acc,
                                 const int* __restrict__ users,
                                 const int* __restrict__ items,
                                 float* __restrict__ out, int B) {
    int gid  = blockIdx.x * blockDim.x + threadIdx.x;
    int b    = gid >> 6;
    int lane = gid & 63;
    if (b >= B) return;
    int u  = users[b];
    int it = N_USERS + items[b];
    float uv = u_acc[(size_t)b * DIM + lane]
             + __half2float(((const __half*)h3)[(size_t)u  * DIM + lane]);
    float iv = it_acc[(size_t)b * DIM + lane]
             + __half2float(((const __half*)h3)[(size_t)it * DIM + lane]);
    float p = uv * iv;
    #pragma unroll
    for (int off = 32; off > 0; off >>= 1)
        p += __shfl_down(p, off, 64);
    if (lane == 0) out[b] = p * (1.0f / 16.0f);
}

extern "C" void kernel_launch(void* const* d_in, const int* in_sizes, int n_in,
                              void* d_out, int out_size, void* d_ws, size_t ws_size,
                              hipStream_t stream) {
    const int*   users = (const int*)d_in[0];
    const int*   items = (const int*)d_in[1];
    const int*   erows = (const int*)d_in[2];
    const int*   ecols = (const int*)d_in[3];
    const float* evals = (const float*)d_in[4];
    const float* uemb  = (const float*)d_in[5];
    const float* iemb  = (const float*)d_in[6];
    const float* temb  = (const float*)d_in[7];
    float* out = (float*)d_out;

    const int n_edges = in_sizes[2];
    const int B       = in_sizes[0];

    const size_t h2bytes = (((size_t)N_NODES * DIM * 2 + 255) / 256) * 256;  // 38.4 MB
    const size_t abytes  = (size_t)B * DIM * sizeof(float);                  // 4.2 MB
    const size_t rpbytes = (((size_t)(N_NODES + 1) * 4 + 255) / 256) * 256;
    const size_t cvbytes = (size_t)n_edges * 8;                              // 40 MB
    const size_t mbytes  = (((size_t)M_TOT * 4 + 255) / 256) * 256;          // 1.2 MB

    char* ws = (char*)d_ws;
    size_t off = 0;
    ushort* hA      = (ushort*)(ws + off); off += h2bytes;
    ushort* hB      = (ushort*)(ws + off); off += h2bytes;
    float*  u_acc   = (float*) (ws + off); off += abytes;
    float*  it_acc  = (float*) (ws + off); off += abytes;
    int*    row_ptr = (int*)   (ws + off); off += rpbytes;
    int2*   csr_cv  = (int2*)  (ws + off); off += cvbytes;
    int2*   bkt_buf = (int2*)  (ws + off); off += cvbytes;
    int*    partial = (int*)   (ws + off); off += mbytes;
    int*    offs    = (int*)   (ws + off); off += mbytes;
    int*    psum    = (int*)   (ws + off); off += 4096;   // ~168 MB total

    dim3 blk(256);

    // ---- CSR build: zero global atomics ----
    bucket_hist_kernel<<<NB, blk, 0, stream>>>(erows, partial, n_edges);
    scanB1_kernel<<<SB, blk, 0, stream>>>(partial, psum);
    scanB2_kernel<<<1,  SB,  0, stream>>>(psum);
    scanB3_kernel<<<SB, blk, 0, stream>>>(partial, psum, offs);
    scatter1_kernel<<<NB, blk, 0, stream>>>(erows, ecols, evals, offs, bkt_buf, n_edges);
    scatter2_kernel<<<NBUCKETS, blk, 0, stream>>>(bkt_buf, offs, row_ptr, csr_cv, n_edges);

    // ---- h0 ----
    const long n4 = (long)N_NODES * DIM / 4;
    concat_f16_kernel<<<(int)((n4 + 255) / 256), blk, 0, stream>>>(uemb, iemb, temb, hA);

    const int gblocks = (B * 16 + 255) / 256;
    gather_add_kernel<<<gblocks, blk, 0, stream>>>(hA, users, items, u_acc, it_acc, B, 1);

    // 4 rows per wave
    const int nwaves  = (N_NODES + 3) / 4;
    const int sblocks = (int)(((long)nwaves * 64 + 255) / 256);
    ushort* src = hA;
    ushort* dst = hB;
    for (int l = 0; l < 3; ++l) {
        spmv_csr_kernel<<<sblocks, blk, 0, stream>>>(row_ptr, csr_cv, src, dst);
        if (l < 2)
            gather_add_kernel<<<gblocks, blk, 0, stream>>>(dst, users, items, u_acc, it_acc, B, 0);
        ushort* t = src; src = dst; dst = t;
    }
    // after 3 swaps, h3 lives in src
    dot_fused_kernel<<<(B * 64 + 255) / 256, blk, 0, stream>>>(src, u_acc, it_acc,
                                                               users, items, out, B);
}

// Round 10
// 602.258 us; speedup vs baseline: 2.5671x; 1.1531x over previous
//
#include <hip/hip_runtime.h>
#include <hip/hip_fp16.h>

#define N_USERS  200000
#define N_ITEMS  100000
#define N_TOPICS 100
#define N_NODES  (N_USERS + N_ITEMS + N_TOPICS)
#define DIM      64
#define BSHIFT   9                                // 512 rows per bucket
#define BROWS    (1 << BSHIFT)
#define NBUCKETS ((N_NODES + BROWS - 1) >> BSHIFT)   // 587
#define COLMASK  0x7FFFF                          // 19 bits (N_NODES < 2^19)
#define NB       512                              // binning blocks
#define NBSHIFT  9
#define M_TOT    (NBUCKETS * NB)                  // 300,544 partials
#define SB       256                              // scan blocks
#define CH       ((M_TOT + SB - 1) / SB)

// ---------- CSR build (zero global atomics) ----------

__global__ void bucket_hist_kernel(const int* __restrict__ rows,
                                   int* __restrict__ partial, int n_edges) {
    __shared__ int h[NBUCKETS];
    for (int i = threadIdx.x; i < NBUCKETS; i += blockDim.x) h[i] = 0;
    __syncthreads();
    int stride = gridDim.x * blockDim.x;
    for (int e = blockIdx.x * blockDim.x + threadIdx.x; e < n_edges; e += stride)
        atomicAdd(&h[((unsigned)rows[e]) >> BSHIFT], 1);
    __syncthreads();
    for (int i = threadIdx.x; i < NBUCKETS; i += blockDim.x)
        partial[blockIdx.x * NBUCKETS + i] = h[i];
}

// Logical L = bucket*NB + block; physical = block*NBUCKETS + bucket.
__device__ __forceinline__ int phys_idx(int L) {
    return (L & (NB - 1)) * NBUCKETS + (L >> NBSHIFT);
}

__global__ void scanB1_kernel(const int* __restrict__ partial,
                              int* __restrict__ psum) {
    __shared__ int s[256];
    int tid = threadIdx.x;
    int c0 = blockIdx.x * CH;
    int c1 = min(M_TOT, c0 + CH);
    int sum = 0;
    for (int L = c0 + tid; L < c1; L += 256) sum += partial[phys_idx(L)];
    s[tid] = sum;
    __syncthreads();
    for (int off = 128; off > 0; off >>= 1) {
        if (tid < off) s[tid] += s[tid + off];
        __syncthreads();
    }
    if (tid == 0) psum[blockIdx.x] = s[0];
}

__global__ void scanB2_kernel(int* __restrict__ psum) {
    __shared__ int s[SB];
    int tid = threadIdx.x;
    s[tid] = psum[tid];
    __syncthreads();
    for (int off = 1; off < SB; off <<= 1) {
        int v = (tid >= off) ? s[tid - off] : 0;
        __syncthreads();
        s[tid] += v;
        __syncthreads();
    }
    psum[tid] = tid ? s[tid - 1] : 0;
}

__global__ void scanB3_kernel(const int* __restrict__ partial,
                              const int* __restrict__ psum,
                              int* __restrict__ offs) {
    __shared__ int tile[256];
    __shared__ int carry;
    int tid = threadIdx.x;
    int c0 = blockIdx.x * CH;
    int c1 = min(M_TOT, c0 + CH);
    if (tid == 0) carry = psum[blockIdx.x];
    __syncthreads();
    for (int base = c0; base < c1; base += 256) {
        int L = base + tid;
        int v = (L < c1) ? partial[phys_idx(L)] : 0;
        tile[tid] = v;
        __syncthreads();
        for (int off = 1; off < 256; off <<= 1) {
            int t = (tid >= off) ? tile[tid - off] : 0;
            __syncthreads();
            tile[tid] += t;
            __syncthreads();
        }
        if (L < c1) offs[L] = carry + tile[tid] - v;
        __syncthreads();
        if (tid == 255) carry += tile[255];
        __syncthreads();
    }
}

// Bin edges into 512-row buckets at exact positions; LDS-only atomics.
__global__ void scatter1_kernel(const int* __restrict__ rows,
                                const int* __restrict__ cols,
                                const float* __restrict__ vals,
                                const int* __restrict__ offs,
                                int2* __restrict__ bkt_buf, int n_edges) {
    __shared__ int lpos[NBUCKETS];
    for (int i = threadIdx.x; i < NBUCKETS; i += blockDim.x)
        lpos[i] = offs[i * NB + blockIdx.x];
    __syncthreads();
    int stride = gridDim.x * blockDim.x;
    for (int e = blockIdx.x * blockDim.x + threadIdx.x; e < n_edges; e += stride) {
        int r = rows[e];
        int b = ((unsigned)r) >> BSHIFT;
        int pos = atomicAdd(&lpos[b], 1);
        int2 p;
        p.x = cols[e] | ((r & (BROWS - 1)) << 19);
        p.y = __float_as_int(vals[e]);
        bkt_buf[pos] = p;
    }
}

// One block per 512-row bucket: LDS row hist, 2-elem/thread scan, emit
// row_ptr directly, place edges into the bucket's contiguous CSR span.
__global__ void scatter2_kernel(const int2* __restrict__ bkt_buf,
                                const int* __restrict__ offs,
                                int* __restrict__ row_ptr,
                                int2* __restrict__ csr_cv, int n_edges) {
    __shared__ int lcnt[BROWS];
    __shared__ int lptr[BROWS];
    __shared__ int lfill[BROWS];
    __shared__ int s[256];
    int b = blockIdx.x;
    int t = threadIdx.x;
    int e0 = offs[b * NB];
    int e1 = (b == NBUCKETS - 1) ? n_edges : offs[(b + 1) * NB];
    lcnt[t] = 0;          lcnt[t + 256] = 0;
    lfill[t] = 0;         lfill[t + 256] = 0;
    __syncthreads();
    for (int e = e0 + t; e < e1; e += blockDim.x)
        atomicAdd(&lcnt[((unsigned)bkt_buf[e].x) >> 19], 1);
    __syncthreads();
    s[t] = lcnt[2 * t] + lcnt[2 * t + 1];
    __syncthreads();
    for (int off = 1; off < 256; off <<= 1) {
        int v = (t >= off) ? s[t - off] : 0;
        __syncthreads();
        s[t] += v;                       // inclusive over pairs
        __syncthreads();
    }
    int base = e0 + (t ? s[t - 1] : 0);
    int rbase = b << BSHIFT;
    int p_even = base;
    int p_odd  = base + lcnt[2 * t];
    lptr[2 * t]     = p_even;
    lptr[2 * t + 1] = p_odd;
    if (rbase + 2 * t     < N_NODES) row_ptr[rbase + 2 * t]     = p_even;
    if (rbase + 2 * t + 1 < N_NODES) row_ptr[rbase + 2 * t + 1] = p_odd;
    if (b == NBUCKETS - 1 && t == 0) row_ptr[N_NODES] = n_edges;
    __syncthreads();
    for (int e = e0 + t; e < e1; e += blockDim.x) {
        int2 p = bkt_buf[e];
        int delta = ((unsigned)p.x) >> 19;
        int pos = lptr[delta] + atomicAdd(&lfill[delta], 1);
        int2 cv;
        cv.x = p.x & COLMASK;
        cv.y = p.y;
        csr_cv[pos] = cv;
    }
}

// ---------- h0 = fp16(concat(user, item, topic)) ----------
__global__ void concat_f16_kernel(const float* __restrict__ uemb,
                                  const float* __restrict__ iemb,
                                  const float* __restrict__ temb,
                                  ushort* __restrict__ h0) {
    int g = blockIdx.x * blockDim.x + threadIdx.x;     // group of 4 elems
    long base = (long)g * 4;
    if (base >= (long)N_NODES * DIM) return;
    const float* src;
    long off;
    if (base < (long)N_USERS * DIM)                 { src = uemb; off = base; }
    else if (base < (long)(N_USERS + N_ITEMS) * DIM){ src = iemb; off = base - (long)N_USERS * DIM; }
    else                                            { src = temb; off = base - (long)(N_USERS + N_ITEMS) * DIM; }
    float4 v = *(const float4*)(src + off);
    __half2 a = __floats2half2_rn(v.x, v.y);
    __half2 b = __floats2half2_rn(v.z, v.w);
    uint2 o;
    o.x = *(unsigned*)&a;
    o.y = *(unsigned*)&b;
    ((uint2*)h0)[g] = o;
}

// ---------- SpMV helpers ----------
// fmaf(half2float(h), w, acc) lowers to v_fma_mix_f32 (fp16 src, fp32 MAC).
__device__ __forceinline__ float4 fma_mix4(const ushort* __restrict__ h,
                                           int row, int l16, float w,
                                           float4 acc) {
    uint2 r = ((const uint2*)(h + (size_t)row * DIM))[l16];
    __half2 h01 = *(__half2*)&r.x;
    __half2 h23 = *(__half2*)&r.y;
    acc.x = __builtin_fmaf(__half2float(__low2half(h01)),  w, acc.x);
    acc.y = __builtin_fmaf(__half2float(__high2half(h01)), w, acc.y);
    acc.z = __builtin_fmaf(__half2float(__low2half(h23)),  w, acc.z);
    acc.w = __builtin_fmaf(__half2float(__high2half(h23)), w, acc.w);
    return acc;
}

// Full-table SpMV: 4 rows/wave (1 per 16-lane group), 8 edges in flight.
__global__ void spmv_csr_kernel(const int* __restrict__ row_ptr,
                                const int2* __restrict__ csr_cv,
                                const ushort* __restrict__ h_src,
                                ushort* __restrict__ h_dst) {
    int wave = (int)(((long)blockIdx.x * blockDim.x + threadIdx.x) >> 6);
    int lane = threadIdx.x & 63;
    int g    = lane >> 4;
    int l16  = lane & 15;
    int r    = wave * 4 + g;
    int rc   = min(r, N_NODES - 1);
    int p0   = row_ptr[rc];
    int p1   = row_ptr[rc + 1];
    int len  = (r < N_NODES) ? (p1 - p0) : 0;
    int m = max(len, __shfl_xor(len, 16, 64));
    m = max(m, __shfl_xor(m, 32, 64));
    float4 acc = make_float4(0.f, 0.f, 0.f, 0.f);
    for (int off = 0; off < m; off += 8) {
        int2 cv[8];
        #pragma unroll
        for (int j = 0; j < 8; ++j) {
            bool k = (off + j) < len;
            cv[j] = csr_cv[k ? (p0 + off + j) : p0];
            if (!k) cv[j].y = 0;
        }
        #pragma unroll
        for (int j = 0; j < 8; ++j)
            acc = fma_mix4(h_src, cv[j].x, l16, __int_as_float(cv[j].y), acc);
    }
    if (r < N_NODES) {
        __half2 a = __floats2half2_rn(acc.x, acc.y);
        __half2 b = __floats2half2_rn(acc.z, acc.w);
        uint2 o;
        o.x = *(unsigned*)&a;
        o.y = *(unsigned*)&b;
        ((uint2*)(h_dst + (size_t)r * DIM))[l16] = o;
    }
}

// Layer-3 SpMV over BATCH ROWS ONLY (~11% of the edges): slot s in [0,2B);
// node = users[s] or N_USERS+items[s-B]. Accumulates A·h2[node] in fp32 and
// adds straight into u_acc/it_acc (slot owned by exactly one group: safe RMW).
__global__ void spmv_batch_kernel(const int* __restrict__ row_ptr,
                                  const int2* __restrict__ csr_cv,
                                  const ushort* __restrict__ h_src,
                                  const int* __restrict__ users,
                                  const int* __restrict__ items,
                                  float* __restrict__ u_acc,
                                  float* __restrict__ it_acc, int B) {
    int wave = (int)(((long)blockIdx.x * blockDim.x + threadIdx.x) >> 6);
    int lane = threadIdx.x & 63;
    int g    = lane >> 4;
    int l16  = lane & 15;
    int s    = wave * 4 + g;
    bool ok  = s < 2 * B;
    int node = 0;
    if (ok) node = (s < B) ? users[s] : (N_USERS + items[s - B]);
    int p0  = row_ptr[node];
    int p1  = row_ptr[node + 1];
    int len = ok ? (p1 - p0) : 0;
    int m = max(len, __shfl_xor(len, 16, 64));
    m = max(m, __shfl_xor(m, 32, 64));
    float4 acc = make_float4(0.f, 0.f, 0.f, 0.f);
    for (int off = 0; off < m; off += 8) {
        int2 cv[8];
        #pragma unroll
        for (int j = 0; j < 8; ++j) {
            bool k = (off + j) < len;
            cv[j] = csr_cv[k ? (p0 + off + j) : p0];
            if (!k) cv[j].y = 0;
        }
        #pragma unroll
        for (int j = 0; j < 8; ++j)
            acc = fma_mix4(h_src, cv[j].x, l16, __int_as_float(cv[j].y), acc);
    }
    if (ok) {
        float* dst = (s < B) ? (u_acc + (size_t)s * DIM)
                             : (it_acc + (size_t)(s - B) * DIM);
        float4* p = (float4*)dst + l16;
        float4 old = *p;
        old.x += acc.x; old.y += acc.y; old.z += acc.z; old.w += acc.w;
        *p = old;
    }
}

// ---------- batch-row accumulation (fp32 acc) + readout ----------

__global__ void gather_add_kernel(const ushort* __restrict__ h,
                                  const int* __restrict__ users,
                                  const int* __restrict__ items,
                                  float* __restrict__ u_acc,
                                  float* __restrict__ it_acc,
                                  int B, int first) {
    int gid  = blockIdx.x * blockDim.x + threadIdx.x;
    int b    = gid >> 4;
    int lane = gid & 15;
    if (b >= B) return;
    int u  = users[b];
    int it = N_USERS + items[b];
    uint2 ur = ((const uint2*)(h + (size_t)u  * DIM))[lane];
    uint2 ir = ((const uint2*)(h + (size_t)it * DIM))[lane];
    float2 u01 = __half22float2(*(__half2*)&ur.x);
    float2 u23 = __half22float2(*(__half2*)&ur.y);
    float2 i01 = __half22float2(*(__half2*)&ir.x);
    float2 i23 = __half22float2(*(__half2*)&ir.y);
    float4* up = (float4*)(u_acc  + (size_t)b * DIM) + lane;
    float4* ip = (float4*)(it_acc + (size_t)b * DIM) + lane;
    if (first) {
        *up = make_float4(u01.x, u01.y, u23.x, u23.y);
        *ip = make_float4(i01.x, i01.y, i23.x, i23.y);
    } else {
        float4 a = *up;
        a.x += u01.x; a.y += u01.y; a.z += u23.x; a.w += u23.y;
        *up = a;
        float4 c = *ip;
        c.x += i01.x; c.y += i01.y; c.z += i23.x; c.w += i23.y;
        *ip = c;
    }
}

__global__ void dot_kernel(const float* __restrict__ u_acc,
                           const float* __restrict__ it_acc,
                           float* __restrict__ out, int B) {
    int gid  = blockIdx.x * blockDim.x + threadIdx.x;
    int b    = gid >> 6;
    int lane = gid & 63;
    if (b >= B) return;
    float p = u_acc[(size_t)b * DIM + lane] * it_acc[(size_t)b * DIM + lane];
    #pragma unroll
    for (int off = 32; off > 0; off >>= 1)
        p += __shfl_down(p, off, 64);
    if (lane == 0) out[b] = p * (1.0f / 16.0f);
}

extern "C" void kernel_launch(void* const* d_in, const int* in_sizes, int n_in,
                              void* d_out, int out_size, void* d_ws, size_t ws_size,
                              hipStream_t stream) {
    const int*   users = (const int*)d_in[0];
    const int*   items = (const int*)d_in[1];
    const int*   erows = (const int*)d_in[2];
    const int*   ecols = (const int*)d_in[3];
    const float* evals = (const float*)d_in[4];
    const float* uemb  = (const float*)d_in[5];
    const float* iemb  = (const float*)d_in[6];
    const float* temb  = (const float*)d_in[7];
    float* out = (float*)d_out;

    const int n_edges = in_sizes[2];
    const int B       = in_sizes[0];

    const size_t h2bytes = (((size_t)N_NODES * DIM * 2 + 255) / 256) * 256;  // 38.4 MB
    const size_t abytes  = (size_t)B * DIM * sizeof(float);                  // 4.2 MB
    const size_t rpbytes = (((size_t)(N_NODES + 1) * 4 + 255) / 256) * 256;
    const size_t cvbytes = (size_t)n_edges * 8;                              // 40 MB
    const size_t mbytes  = (((size_t)M_TOT * 4 + 255) / 256) * 256;          // 1.2 MB

    char* ws = (char*)d_ws;
    size_t off = 0;
    ushort* hA      = (ushort*)(ws + off); off += h2bytes;
    ushort* hB      = (ushort*)(ws + off); off += h2bytes;
    float*  u_acc   = (float*) (ws + off); off += abytes;
    float*  it_acc  = (float*) (ws + off); off += abytes;
    int*    row_ptr = (int*)   (ws + off); off += rpbytes;
    int2*   csr_cv  = (int2*)  (ws + off); off += cvbytes;
    int2*   bkt_buf = (int2*)  (ws + off); off += cvbytes;
    int*    partial = (int*)   (ws + off); off += mbytes;
    int*    offs    = (int*)   (ws + off); off += mbytes;
    int*    psum    = (int*)   (ws + off); off += 4096;   // ~168 MB total

    dim3 blk(256);

    // ---- CSR build: zero global atomics ----
    bucket_hist_kernel<<<NB, blk, 0, stream>>>(erows, partial, n_edges);
    scanB1_kernel<<<SB, blk, 0, stream>>>(partial, psum);
    scanB2_kernel<<<1,  SB,  0, stream>>>(psum);
    scanB3_kernel<<<SB, blk, 0, stream>>>(partial, psum, offs);
    scatter1_kernel<<<NB, blk, 0, stream>>>(erows, ecols, evals, offs, bkt_buf, n_edges);
    scatter2_kernel<<<NBUCKETS, blk, 0, stream>>>(bkt_buf, offs, row_ptr, csr_cv, n_edges);

    // ---- h0 ----
    const long n4 = (long)N_NODES * DIM / 4;
    concat_f16_kernel<<<(int)((n4 + 255) / 256), blk, 0, stream>>>(uemb, iemb, temb, hA);

    const int gblocks = (B * 16 + 255) / 256;
    gather_add_kernel<<<gblocks, blk, 0, stream>>>(hA, users, items, u_acc, it_acc, B, 1);

    // ---- layers 1,2: full-table SpMV; layer 3: batch rows only ----
    const int nwaves  = (N_NODES + 3) / 4;
    const int sblocks = (int)(((long)nwaves * 64 + 255) / 256);
    ushort* src = hA;
    ushort* dst = hB;
    for (int l = 0; l < 2; ++l) {
        spmv_csr_kernel<<<sblocks, blk, 0, stream>>>(row_ptr, csr_cv, src, dst);
        gather_add_kernel<<<gblocks, blk, 0, stream>>>(dst, users, items, u_acc, it_acc, B, 0);
        ushort* t = src; src = dst; dst = t;
    }
    // src == h2
    const int bwaves  = (2 * B + 3) / 4;
    const int bblocks = (int)(((long)bwaves * 64 + 255) / 256);
    spmv_batch_kernel<<<bblocks, blk, 0, stream>>>(row_ptr, csr_cv, src,
                                                   users, items, u_acc, it_acc, B);

    dot_kernel<<<(B * 64 + 255) / 256, blk, 0, stream>>>(u_acc, it_acc, out, B);
}